// Round 8
// baseline (596.897 us; speedup 1.0000x reference)
//
#include <hip/hip_runtime.h>

#define N_NODES 100000
#define N_EDGES 1200000
#define NCLS 81  // 65 deg classes + 16 lab classes

typedef unsigned short u16;
typedef unsigned int u32;
typedef short bf16x8 __attribute__((ext_vector_type(8)));
typedef float f32x4 __attribute__((ext_vector_type(4)));

__device__ __forceinline__ float b2f(u16 u) {
  union { u32 i; float f; } v; v.i = ((u32)u) << 16; return v.f;
}
__device__ __forceinline__ u16 f2b(float f) {
  union { float f; u32 i; } v; v.f = f;
  u32 x = v.i;
  return (u16)((x + 0x7fffu + ((x >> 16) & 1u)) >> 16);
}
__device__ __forceinline__ u32 pk2(float lo, float hi) {
  return (u32)f2b(lo) | ((u32)f2b(hi) << 16);
}
__device__ __forceinline__ void up2(u32 w, float& lo, float& hi) {
  union { u32 u; float f; } a, b;
  a.u = w << 16; b.u = w & 0xffff0000u;
  lo = a.f; hi = b.f;
}
__device__ __forceinline__ float lrelu(float x) { return x > 0.f ? x : 0.01f * x; }

// ---- fp32 param block offsets ----
#define P_EMBD 0       // 4160
#define P_EMBL 4160    // 1024
#define P_W1A  5184    // 16384  l0_w1 (128x128)
#define P_B1A  21568   // 128
#define P_W2A  21696   // 8192   l0_w2 (128x64)
#define P_B2A  29888   // 64
#define P_EPS0 29952   // 1
#define P_G0   29953   // 64
#define P_BB0  30017   // 64
#define P_LW1  30081   // 4096   l1_w1 (64x64)
#define P_LB1  34177   // 64
#define P_LW2  34241   // 4096   l1_w2 (64x64)
#define P_LB2  38337   // 64
#define P_EPS1 38401   // 1
#define P_G1   38402   // 64
#define P_BB1  38466   // 64
#define P_FW1  38530   // 16384  fc_w1 (256x64)
#define P_FB1  54914   // 64
#define P_FG   54978   // 64
#define P_FBB  55042   // 64
#define P_FW2  55106   // 64
#define P_FB2  55170   // 1
#define P_TOT  55171

// ---------------- dtype detection ----------------
__global__ void k_detect(const u16* __restrict__ e, u32* __restrict__ flag) {
  u32 t = 0;
  for (int k = threadIdx.x; k < 4096; k += 256) {
    u32 ex = (e[k] >> 7) & 0xFF;
    if (ex >= 0x90) t = 1;
  }
  if (t) atomicOr(flag, 1u);
}

// ---------------- convert all float params to fp32 block ----------------
struct CvtAll {
  const void* src[22];
  int cnt[22];
  int off[22];
};

__global__ void k_cvtall(CvtAll a, const u32* __restrict__ flag, float* __restrict__ P) {
  int seg = blockIdx.y;
  int i = blockIdx.x * 256 + threadIdx.x;
  if (i >= a.cnt[seg]) return;
  float v;
  if (*flag) v = ((const float*)a.src[seg])[i];
  else       v = b2f(((const u16*)a.src[seg])[i]);
  P[a.off[seg] + i] = v;
}

// ---------------- merged preprocessing: W1p, Efc, MFMA B-pack ----------------
__global__ void k_prep(const float* __restrict__ P, float* __restrict__ W1p,
                       float* __restrict__ Efc, u16* __restrict__ bp) {
  int idx = blockIdx.x * 256 + threadIdx.x;
  if (idx < NCLS * 128) {
    int c = idx >> 7, h = idx & 127;
    const float* w1 = P + P_W1A;
    float s = 0.f;
    if (c < 65) {
      const float* em = P + P_EMBD + c * 64;
      for (int k = 0; k < 64; ++k) s = fmaf(em[k], w1[k * 128 + h], s);
    } else {
      const float* em = P + P_EMBL + (c - 65) * 64;
      for (int k = 0; k < 64; ++k) s = fmaf(em[k], w1[(64 + k) * 128 + h], s);
    }
    W1p[idx] = s;
    return;
  }
  if (idx < NCLS * 128 + NCLS * 64) {
    int r = idx - NCLS * 128;
    int c = r >> 6, o = r & 63;
    const float* fw = P + P_FW1;
    float s = 0.f;
    if (c < 65) {
      const float* em = P + P_EMBD + c * 64;
      for (int k = 0; k < 64; ++k) s = fmaf(em[k], fw[k * 64 + o], s);
    } else {
      const float* em = P + P_EMBL + (c - 65) * 64;
      for (int k = 0; k < 64; ++k) s = fmaf(em[k], fw[(64 + k) * 64 + o], s);
    }
    Efc[r] = s;
    return;
  }
  int pidx = idx - (NCLS * 128 + NCLS * 64);
  if (pidx >= 24576) return;
  int seg, rel;
  if (pidx < 8192)       { seg = 0; rel = pidx; }
  else if (pidx < 12288) { seg = 1; rel = pidx - 8192; }
  else if (pidx < 16384) { seg = 2; rel = pidx - 12288; }
  else                   { seg = 3; rel = pidx - 16384; }
  const int srcoff[4] = {P_W2A, P_LW1, P_LW2, P_FW1 + 128 * 64};
  const int KBs[4] = {4, 2, 2, 4};
  int j = rel & 7, lane = (rel >> 3) & 63, rest = rel >> 9;
  int kb = rest % KBs[seg], nt = rest / KBs[seg];
  int k = kb * 32 + (lane >> 4) * 8 + j;
  int n = nt * 16 + (lane & 15);
  bp[pidx] = f2b(P[srcoff[seg] + k * 64 + n]);
}

// ---------------- in-degree (u32 atomics) ----------------
__global__ void k_deg(const int* __restrict__ edge, u32* __restrict__ deg) {
  int e = blockIdx.x * 256 + threadIdx.x;
  if (e >= N_EDGES) return;
  atomicAdd(&deg[edge[N_EDGES + e]], 1u);
}

// ---------------- CSR build: scan of deg ----------------
__global__ void k_scan1(const u32* __restrict__ deg, u32* __restrict__ row_ptr,
                        u32* __restrict__ bsum) {
  __shared__ u32 l[256];
  int tid = threadIdx.x;
  int i = blockIdx.x * 256 + tid;
  u32 v = (i < N_NODES) ? deg[i] : 0u;
  l[tid] = v;
  __syncthreads();
  for (int off = 1; off < 256; off <<= 1) {
    u32 a = (tid >= off) ? l[tid - off] : 0u;
    __syncthreads();
    l[tid] += a;
    __syncthreads();
  }
  if (i < N_NODES) row_ptr[i] = l[tid] - v;  // within-block exclusive
  if (tid == 255) bsum[blockIdx.x] = l[255];
}

#define NBLK_SCAN 391

__global__ void k_scan2(u32* __restrict__ bsum) {
  __shared__ u32 l[512];
  int tid = threadIdx.x;
  u32 v = (tid < NBLK_SCAN) ? bsum[tid] : 0u;
  l[tid] = v;
  __syncthreads();
  for (int off = 1; off < 512; off <<= 1) {
    u32 a = (tid >= off) ? l[tid - off] : 0u;
    __syncthreads();
    l[tid] += a;
    __syncthreads();
  }
  if (tid < NBLK_SCAN) bsum[tid] = l[tid] - v;  // exclusive block offsets
}

// ---------------- CSR fill: single packed u32 scatter ----------------
// einfo = src(17b) << 11 | ndeg(7b) << 4 | nlab(4b)
__global__ void k_fill(const int* __restrict__ edge, const int* __restrict__ ndeg,
                       const int* __restrict__ nlab, u32* __restrict__ rp,
                       const u32* __restrict__ bsum, u32* __restrict__ einfo) {
  int e = blockIdx.x * 256 + threadIdx.x;
  if (e >= N_EDGES) return;
  int s = edge[e], d = edge[N_EDGES + e];
  u32 pos = atomicAdd(&rp[d], 1u) + bsum[d >> 8];
  einfo[pos] = ((u32)s << 11) | ((u32)ndeg[s] << 4) | (u32)nlab[s];
}

__device__ __forceinline__ u32 row_start(const u32* rp, const u32* bsum, int n) {
  return (n == 0) ? 0u : rp[n - 1] + bsum[(n - 1) >> 8];
}
__device__ __forceinline__ u32 row_end(const u32* rp, const u32* bsum, int n) {
  return rp[n] + bsum[n >> 8];  // rp[n] was bumped by deg(n) during fill
}

// ---------------- layer-0 aggregation: bf16 LDS W1p, 4-deep pipelined ----------------
__global__ __launch_bounds__(256) void k_agg0(const u32* __restrict__ rp,
                                              const u32* __restrict__ bsum,
                                              const u32* __restrict__ einfo,
                                              const int* __restrict__ ndeg,
                                              const int* __restrict__ nlab,
                                              const float* __restrict__ W1p,
                                              const float* __restrict__ P,
                                              u16* __restrict__ hmid) {
  __shared__ u32 w[NCLS * 64];  // packed bf16 pairs, 20736 B
  for (int i = threadIdx.x; i < NCLS * 64; i += 256) {
    float2 v = ((const float2*)W1p)[i];
    w[i] = pk2(v.x, v.y);
  }
  __syncthreads();
  int lane = threadIdx.x & 63, wv = threadIdx.x >> 6;
  float onep = 1.f + P[P_EPS0];
  float2 b1v = ((const float2*)(P + P_B1A))[lane];
#pragma unroll 1
  for (int it = 0; it < 16; ++it) {
    int n = blockIdx.x * 64 + it * 4 + wv;
    if (n >= N_NODES) continue;
    int dn = ndeg[n], ln = 65 + nlab[n];
    float x0, x1, y0, y1;
    up2(w[dn * 64 + lane], x0, x1);
    up2(w[ln * 64 + lane], y0, y1);
    float s00 = b1v.x + onep * (x0 + y0), s01 = b1v.y + onep * (x1 + y1);
    float s10 = 0.f, s11 = 0.f, s20 = 0.f, s21 = 0.f, s30 = 0.f, s31 = 0.f;
    u32 rb = row_start(rp, bsum, n), re = row_end(rp, bsum, n);
    for (u32 base = rb; base < re; base += 64) {
      u32 m = re - base; if (m > 64u) m = 64u;
      u32 myc = ((u32)lane < m) ? einfo[base + lane] : 0u;
      u32 kk = 0;
      for (; kk + 4 <= m; kk += 4) {
        u32 q0 = (u32)__builtin_amdgcn_readlane((int)myc, (int)kk);
        u32 q1 = (u32)__builtin_amdgcn_readlane((int)myc, (int)(kk + 1));
        u32 q2 = (u32)__builtin_amdgcn_readlane((int)myc, (int)(kk + 2));
        u32 q3 = (u32)__builtin_amdgcn_readlane((int)myc, (int)(kk + 3));
        u32 A0 = w[((q0 >> 4) & 0x7Fu) * 64 + lane], B0 = w[(65u + (q0 & 15u)) * 64 + lane];
        u32 A1 = w[((q1 >> 4) & 0x7Fu) * 64 + lane], B1 = w[(65u + (q1 & 15u)) * 64 + lane];
        u32 A2 = w[((q2 >> 4) & 0x7Fu) * 64 + lane], B2 = w[(65u + (q2 & 15u)) * 64 + lane];
        u32 A3 = w[((q3 >> 4) & 0x7Fu) * 64 + lane], B3 = w[(65u + (q3 & 15u)) * 64 + lane];
        float t0, t1;
        up2(A0, t0, t1); s00 += t0; s01 += t1;
        up2(B0, t0, t1); s00 += t0; s01 += t1;
        up2(A1, t0, t1); s10 += t0; s11 += t1;
        up2(B1, t0, t1); s10 += t0; s11 += t1;
        up2(A2, t0, t1); s20 += t0; s21 += t1;
        up2(B2, t0, t1); s20 += t0; s21 += t1;
        up2(A3, t0, t1); s30 += t0; s31 += t1;
        up2(B3, t0, t1); s30 += t0; s31 += t1;
      }
      for (; kk < m; ++kk) {
        u32 q0 = (u32)__builtin_amdgcn_readlane((int)myc, (int)kk);
        u32 A0 = w[((q0 >> 4) & 0x7Fu) * 64 + lane], B0 = w[(65u + (q0 & 15u)) * 64 + lane];
        float t0, t1;
        up2(A0, t0, t1); s00 += t0; s01 += t1;
        up2(B0, t0, t1); s00 += t0; s01 += t1;
      }
    }
    float a0 = (s00 + s10) + (s20 + s30);
    float a1 = (s01 + s11) + (s21 + s31);
    ((u32*)hmid)[(size_t)n * 64 + lane] = pk2(lrelu(a0), lrelu(a1));
  }
}

// ---------------- MFMA GEMM: C[100k,64] = A[100k,K] @ B + (bias) ----------------
// BLOCKED=1: write C feature-block-major: C[((nt*N + m)*16 + row)]
template <int KB, int LDA, int BIASOFF, int BLOCKED>
__global__ __launch_bounds__(256) void k_gemm(const u16* __restrict__ A,
                                              const u16* __restrict__ Bp,
                                              const float* __restrict__ P,
                                              u16* __restrict__ C) {
  int wid = threadIdx.x >> 6, lane = threadIdx.x & 63;
  int m0 = (blockIdx.x * 4 + wid) * 16;
  if (m0 >= N_NODES) return;
  int row = lane & 15, q = lane >> 4;
  const u16* ap = A + (size_t)(m0 + row) * LDA + q * 8;
  const bf16x8* bp = (const bf16x8*)Bp;
  f32x4 acc[4];
#pragma unroll
  for (int nt = 0; nt < 4; ++nt) {
    float b = (BIASOFF >= 0) ? P[BIASOFF + nt * 16 + row] : 0.f;
    acc[nt][0] = b; acc[nt][1] = b; acc[nt][2] = b; acc[nt][3] = b;
  }
#pragma unroll
  for (int kb = 0; kb < KB; ++kb) {
    bf16x8 af = *(const bf16x8*)(ap + kb * 32);
#pragma unroll
    for (int nt = 0; nt < 4; ++nt) {
      bf16x8 bf = bp[(nt * KB + kb) * 64 + lane];
      acc[nt] = __builtin_amdgcn_mfma_f32_16x16x32_bf16(af, bf, acc[nt], 0, 0, 0);
    }
  }
#pragma unroll
  for (int nt = 0; nt < 4; ++nt)
#pragma unroll
    for (int r = 0; r < 4; ++r) {
      int m = m0 + q * 4 + r;
      if (BLOCKED) C[((size_t)nt * N_NODES + m) * 16 + row] = f2b(acc[nt][r]);
      else         C[(size_t)m * 64 + nt * 16 + row] = f2b(acc[nt][r]);
    }
}

// fc1 variant: + Efc[dn]+Efc[ln] row add in epilogue
__global__ __launch_bounds__(256) void k_gemm_fc1(const u16* __restrict__ A,
                                                  const u16* __restrict__ Bp,
                                                  const float* __restrict__ P,
                                                  const int* __restrict__ ndeg,
                                                  const int* __restrict__ nlab,
                                                  const float* __restrict__ Efc,
                                                  u16* __restrict__ C) {
  const int KB = 4, LDA = 128;
  int wid = threadIdx.x >> 6, lane = threadIdx.x & 63;
  int m0 = (blockIdx.x * 4 + wid) * 16;
  if (m0 >= N_NODES) return;
  int row = lane & 15, q = lane >> 4;
  const u16* ap = A + (size_t)(m0 + row) * LDA + q * 8;
  const bf16x8* bp = (const bf16x8*)Bp;
  f32x4 acc[4];
#pragma unroll
  for (int nt = 0; nt < 4; ++nt) {
    float b = P[P_FB1 + nt * 16 + row];
    acc[nt][0] = b; acc[nt][1] = b; acc[nt][2] = b; acc[nt][3] = b;
  }
#pragma unroll
  for (int kb = 0; kb < KB; ++kb) {
    bf16x8 af = *(const bf16x8*)(ap + kb * 32);
#pragma unroll
    for (int nt = 0; nt < 4; ++nt) {
      bf16x8 bf = bp[(nt * KB + kb) * 64 + lane];
      acc[nt] = __builtin_amdgcn_mfma_f32_16x16x32_bf16(af, bf, acc[nt], 0, 0, 0);
    }
  }
#pragma unroll
  for (int r = 0; r < 4; ++r) {
    int m = m0 + q * 4 + r;
    int dn = ndeg[m], ln = 65 + nlab[m];
#pragma unroll
    for (int nt = 0; nt < 4; ++nt) {
      int cc = nt * 16 + row;
      float v = acc[nt][r] + Efc[dn * 64 + cc] + Efc[ln * 64 + cc];
      C[(size_t)m * 64 + cc] = f2b(v);
    }
  }
}

// ---------------- layer-1 aggregation: feature-blocked, L2-resident passes ----------
// g1b layout: [pass][n][16]; pass footprint 3.2 MB < 4 MB per-XCD L2.
// wave = 1 node: lanes = 4 edges x 16 feats; xor-reduce over edge subgroups.
#define AGG1_NB 25000  // nodes/4
__global__ __launch_bounds__(256) void k_agg1(const u32* __restrict__ rp,
                                              const u32* __restrict__ bsum,
                                              const u32* __restrict__ einfo,
                                              const u16* __restrict__ g1b,
                                              const float* __restrict__ P,
                                              u16* __restrict__ abuf) {
  int pass = blockIdx.x / AGG1_NB;
  int nb = blockIdx.x % AGG1_NB;
  int wv = threadIdx.x >> 6, lane = threadIdx.x & 63;
  int sub = lane >> 4, f = lane & 15;
  int n = nb * 4 + wv;
  u32 st = row_start(rp, bsum, n), en = row_end(rp, bsum, n);
  u32 m = en - st;
  const u16* gp = g1b + (size_t)pass * N_NODES * 16;
  float acc = 0.f;
  u32 k = 0;
  for (; k + 8 <= m; k += 8) {
    u32 s0 = einfo[st + k + sub] >> 11;
    u32 s1 = einfo[st + k + 4 + sub] >> 11;
    float v0 = b2f(gp[(size_t)s0 * 16 + f]);
    float v1 = b2f(gp[(size_t)s1 * 16 + f]);
    acc += v0 + v1;
  }
  if (k + 4 <= m) {
    u32 s0 = einfo[st + k + sub] >> 11;
    acc += b2f(gp[(size_t)s0 * 16 + f]);
    k += 4;
  }
  if (k + (u32)sub < m) {
    u32 s0 = einfo[st + k + sub] >> 11;
    acc += b2f(gp[(size_t)s0 * 16 + f]);
  }
  acc += __shfl_xor(acc, 16, 64);
  acc += __shfl_xor(acc, 32, 64);
  if (sub == 0) {
    float onep = 1.f + P[P_EPS1];
    float self = b2f(gp[(size_t)n * 16 + f]);
    float a = P[P_LB1 + pass * 16 + f] + fmaf(onep, self, acc);
    abuf[(size_t)n * 64 + pass * 16 + f] = f2b(lrelu(a));
  }
}

// ---------------- BatchNorm stats over bf16 t ----------------
__global__ void k_bnstats(const u16* __restrict__ t, float* __restrict__ stats) {
  __shared__ float ls[256], lq[256];
  int tid = threadIdx.x;
  int f = tid & 63, rg = tid >> 6;
  float s = 0.f, q = 0.f;
  for (int n = blockIdx.x * 4 + rg; n < N_NODES; n += gridDim.x * 4) {
    float v = b2f(t[(size_t)n * 64 + f]);
    s += v;
    q = fmaf(v, v, q);
  }
  ls[tid] = s; lq[tid] = q;
  __syncthreads();
  if (tid < 64) {
    s = ls[tid] + ls[tid + 64] + ls[tid + 128] + ls[tid + 192];
    q = lq[tid] + lq[tid + 64] + lq[tid + 128] + lq[tid + 192];
    atomicAdd(&stats[f], s);
    atomicAdd(&stats[64 + f], q);
  }
}

// ---------------- BN finalize + lrelu -> h12 (stride 128, offset dof) ----------------
__global__ void k_bnfin(const u16* __restrict__ t, const float* __restrict__ stats,
                        const float* __restrict__ P, int goff, int boff,
                        u16* __restrict__ h, int dof) {
  int idx = blockIdx.x * blockDim.x + threadIdx.x;
  if (idx >= N_NODES * 64) return;
  int f = idx & 63, n = idx >> 6;
  const float invN = 1.f / (float)N_NODES;
  float m = stats[f] * invN;
  float var = fmaxf(stats[64 + f] * invN - m * m, 0.f);
  float inv = rsqrtf(var + 1e-5f);
  float v = (b2f(t[idx]) - m) * inv * P[goff + f] + P[boff + f];
  v = lrelu(v);
  if (!(fabsf(v) < 1e30f)) v = 999.0f;
  h[(size_t)n * 128 + dof + f] = f2b(v);
}

// ---------------- FC final: BN + lrelu + dot + sigmoid ----------------
__global__ void k_fc2(const u16* __restrict__ t, const float* __restrict__ stats,
                      const float* __restrict__ P, const u32* __restrict__ flag,
                      void* __restrict__ out) {
  int n = blockIdx.x * blockDim.x + threadIdx.x;
  if (n >= N_NODES) return;
  float z = P[P_FB2];
  const float invN = 1.f / (float)N_NODES;
  const u16* tn = t + (size_t)n * 64;
#pragma unroll 1
  for (int f = 0; f < 64; ++f) {
    float m = stats[f] * invN;
    float var = fmaxf(stats[64 + f] * invN - m * m, 0.f);
    float inv = rsqrtf(var + 1e-5f);
    float y = (b2f(tn[f]) - m) * inv * P[P_FG + f] + P[P_FBB + f];
    y = lrelu(y);
    z = fmaf(y, P[P_FW2 + f], z);
  }
  float s = 1.f / (1.f + expf(-z));
  if (!(fabsf(z) < 1e30f)) s = 0.25f;
  if (*flag) ((float*)out)[n] = s;
  else       ((u16*)out)[n] = f2b(s);
}

extern "C" void kernel_launch(void* const* d_in, const int* in_sizes, int n_in,
                              void* d_out, int out_size, void* d_ws, size_t ws_size,
                              hipStream_t stream) {
  const int* node_deg = (const int*)d_in[0];
  const int* node_lab = (const int*)d_in[1];
  const int* edge     = (const int*)d_in[2];
  (void)in_sizes; (void)n_in; (void)out_size; (void)ws_size;

  char* base = (char*)d_ws;
  size_t off = 0;
  auto alloc = [&](size_t bytes) -> void* {
    void* p = base + off;
    off += (bytes + 15) & ~(size_t)15;
    return p;
  };
  float* Pb    = (float*)alloc((size_t)P_TOT * 4);
  // contiguous zero region: flag | stats | deg  (one memset)
  u32* flag    = (u32*)alloc(16);
  float* stats = (float*)alloc(384 * 4);
  u32* deg     = (u32*)alloc((size_t)N_NODES * 4);
  float* W1p   = (float*)alloc(NCLS * 128 * 4);
  float* Efc   = (float*)alloc(NCLS * 64 * 4);
  u16* bpack   = (u16*)alloc(24576 * 2);
  u32* row_ptr = (u32*)alloc((size_t)(N_NODES + 1) * 4);
  u32* bsum    = (u32*)alloc(512 * 4);
  u32* einfo   = (u32*)alloc((size_t)N_EDGES * 4);
  void* arena  = alloc((size_t)N_NODES * 128 * 2);  // hmid; later g1b+abuf
  u16* h12     = (u16*)alloc((size_t)N_NODES * 128 * 2);
  u16* t       = (u16*)alloc((size_t)N_NODES * 64 * 2);
  u16* hmid = (u16*)arena;
  u16* g1b  = (u16*)arena;                              // [4][N][16] feature-blocked
  u16* abuf = (u16*)arena + (size_t)N_NODES * 64;
  u16* Bp_w2a = bpack;           // 8192
  u16* Bp_lw1 = bpack + 8192;    // 4096
  u16* Bp_lw2 = bpack + 12288;   // 4096
  u16* Bp_fw1 = bpack + 16384;   // 8192

  hipMemsetAsync(flag, 0, 16 + 384 * 4 + (size_t)N_NODES * 4, stream);

  k_detect<<<1, 256, 0, stream>>>((const u16*)d_in[3], flag);

  CvtAll ca;
  const int srcidx[22] = {3, 4, 5, 6, 7, 8, 9, 10, 11, 12, 13, 14, 15, 16, 17, 18, 19, 20, 21, 22, 23, 24};
  const int cnts[22]   = {4160, 1024, 16384, 128, 8192, 64, 1, 64, 64, 4096, 64, 4096, 64, 1, 64, 64, 16384, 64, 64, 64, 64, 1};
  const int offs[22]   = {P_EMBD, P_EMBL, P_W1A, P_B1A, P_W2A, P_B2A, P_EPS0, P_G0, P_BB0,
                          P_LW1, P_LB1, P_LW2, P_LB2, P_EPS1, P_G1, P_BB1,
                          P_FW1, P_FB1, P_FG, P_FBB, P_FW2, P_FB2};
  for (int i = 0; i < 22; ++i) { ca.src[i] = d_in[srcidx[i]]; ca.cnt[i] = cnts[i]; ca.off[i] = offs[i]; }
  k_cvtall<<<dim3(64, 22), 256, 0, stream>>>(ca, flag, Pb);

  k_prep<<<157, 256, 0, stream>>>(Pb, W1p, Efc, bpack);

  // CSR build (no scan3/cursor: fill bumps row_ptr, consumers add bsum)
  k_deg<<<(N_EDGES + 255) / 256, 256, 0, stream>>>(edge, deg);
  k_scan1<<<NBLK_SCAN, 256, 0, stream>>>(deg, row_ptr, bsum);
  k_scan2<<<1, 512, 0, stream>>>(bsum);
  k_fill<<<(N_EDGES + 255) / 256, 256, 0, stream>>>(edge, node_deg, node_lab, row_ptr, bsum, einfo);

  const int GEMM_GRID = (6250 + 3) / 4;

  // layer 0
  k_agg0<<<(N_NODES + 63) / 64, 256, 0, stream>>>(row_ptr, bsum, einfo, node_deg, node_lab, W1p, Pb, hmid);
  k_gemm<4, 128, P_B2A, 0><<<GEMM_GRID, 256, 0, stream>>>(hmid, Bp_w2a, Pb, t);
  k_bnstats<<<512, 256, 0, stream>>>(t, stats);
  k_bnfin<<<(N_NODES * 64 + 255) / 256, 256, 0, stream>>>(t, stats, Pb, P_G0, P_BB0, h12, 0);

  // layer 1: GEMM-first (blocked g1), L2-resident blocked aggregation, GEMM
  k_gemm<2, 128, -1, 1><<<GEMM_GRID, 256, 0, stream>>>(h12, Bp_lw1, Pb, g1b);
  k_agg1<<<AGG1_NB * 4, 256, 0, stream>>>(row_ptr, bsum, einfo, g1b, Pb, abuf);
  k_gemm<2, 64, P_LB2, 0><<<GEMM_GRID, 256, 0, stream>>>(abuf, Bp_lw2, Pb, t);
  k_bnstats<<<512, 256, 0, stream>>>(t, stats + 128);
  k_bnfin<<<(N_NODES * 64 + 255) / 256, 256, 0, stream>>>(t, stats + 128, Pb, P_G1, P_BB1, h12, 64);

  // FC head
  k_gemm_fc1<<<GEMM_GRID, 256, 0, stream>>>(h12, Bp_fw1, Pb, node_deg, node_lab, Efc, t);
  k_bnstats<<<512, 256, 0, stream>>>(t, stats + 256);
  k_fc2<<<(N_NODES + 255) / 256, 256, 0, stream>>>(t, stats + 256, Pb, flag, d_out);
}

// Round 9
// 515.811 us; speedup vs baseline: 1.1572x; 1.1572x over previous
//
#include <hip/hip_runtime.h>

#define N_NODES 100000
#define N_EDGES 1200000
#define NCLS 81  // 65 deg classes + 16 lab classes

typedef unsigned short u16;
typedef unsigned int u32;
typedef short bf16x8 __attribute__((ext_vector_type(8)));
typedef float f32x4 __attribute__((ext_vector_type(4)));

__device__ __forceinline__ float b2f(u16 u) {
  union { u32 i; float f; } v; v.i = ((u32)u) << 16; return v.f;
}
__device__ __forceinline__ u16 f2b(float f) {
  union { float f; u32 i; } v; v.f = f;
  u32 x = v.i;
  return (u16)((x + 0x7fffu + ((x >> 16) & 1u)) >> 16);
}
__device__ __forceinline__ u32 pk2(float lo, float hi) {
  return (u32)f2b(lo) | ((u32)f2b(hi) << 16);
}
__device__ __forceinline__ void up2(u32 w, float& lo, float& hi) {
  union { u32 u; float f; } a, b;
  a.u = w << 16; b.u = w & 0xffff0000u;
  lo = a.f; hi = b.f;
}
__device__ __forceinline__ float lrelu(float x) { return x > 0.f ? x : 0.01f * x; }

// ---- fp32 param block offsets ----
#define P_EMBD 0       // 4160
#define P_EMBL 4160    // 1024
#define P_W1A  5184    // 16384  l0_w1 (128x128)
#define P_B1A  21568   // 128
#define P_W2A  21696   // 8192   l0_w2 (128x64)
#define P_B2A  29888   // 64
#define P_EPS0 29952   // 1
#define P_G0   29953   // 64
#define P_BB0  30017   // 64
#define P_LW1  30081   // 4096   l1_w1 (64x64)
#define P_LB1  34177   // 64
#define P_LW2  34241   // 4096   l1_w2 (64x64)
#define P_LB2  38337   // 64
#define P_EPS1 38401   // 1
#define P_G1   38402   // 64
#define P_BB1  38466   // 64
#define P_FW1  38530   // 16384  fc_w1 (256x64)
#define P_FB1  54914   // 64
#define P_FG   54978   // 64
#define P_FBB  55042   // 64
#define P_FW2  55106   // 64
#define P_FB2  55170   // 1
#define P_TOT  55171

// ---------------- dtype detection ----------------
__global__ void k_detect(const u16* __restrict__ e, u32* __restrict__ flag) {
  u32 t = 0;
  for (int k = threadIdx.x; k < 4096; k += 256) {
    u32 ex = (e[k] >> 7) & 0xFF;
    if (ex >= 0x90) t = 1;
  }
  if (t) atomicOr(flag, 1u);
}

// ---------------- convert all float params to fp32 block ----------------
struct CvtAll {
  const void* src[22];
  int cnt[22];
  int off[22];
};

__global__ void k_cvtall(CvtAll a, const u32* __restrict__ flag, float* __restrict__ P) {
  int seg = blockIdx.y;
  int i = blockIdx.x * 256 + threadIdx.x;
  if (i >= a.cnt[seg]) return;
  float v;
  if (*flag) v = ((const float*)a.src[seg])[i];
  else       v = b2f(((const u16*)a.src[seg])[i]);
  P[a.off[seg] + i] = v;
}

// ---------------- merged preprocessing: W1p, Efc, MFMA B-pack ----------------
__global__ void k_prep(const float* __restrict__ P, float* __restrict__ W1p,
                       float* __restrict__ Efc, u16* __restrict__ bp) {
  int idx = blockIdx.x * 256 + threadIdx.x;
  if (idx < NCLS * 128) {
    int c = idx >> 7, h = idx & 127;
    const float* w1 = P + P_W1A;
    float s = 0.f;
    if (c < 65) {
      const float* em = P + P_EMBD + c * 64;
      for (int k = 0; k < 64; ++k) s = fmaf(em[k], w1[k * 128 + h], s);
    } else {
      const float* em = P + P_EMBL + (c - 65) * 64;
      for (int k = 0; k < 64; ++k) s = fmaf(em[k], w1[(64 + k) * 128 + h], s);
    }
    W1p[idx] = s;
    return;
  }
  if (idx < NCLS * 128 + NCLS * 64) {
    int r = idx - NCLS * 128;
    int c = r >> 6, o = r & 63;
    const float* fw = P + P_FW1;
    float s = 0.f;
    if (c < 65) {
      const float* em = P + P_EMBD + c * 64;
      for (int k = 0; k < 64; ++k) s = fmaf(em[k], fw[k * 64 + o], s);
    } else {
      const float* em = P + P_EMBL + (c - 65) * 64;
      for (int k = 0; k < 64; ++k) s = fmaf(em[k], fw[(64 + k) * 64 + o], s);
    }
    Efc[r] = s;
    return;
  }
  int pidx = idx - (NCLS * 128 + NCLS * 64);
  if (pidx >= 24576) return;
  int seg, rel;
  if (pidx < 8192)       { seg = 0; rel = pidx; }
  else if (pidx < 12288) { seg = 1; rel = pidx - 8192; }
  else if (pidx < 16384) { seg = 2; rel = pidx - 12288; }
  else                   { seg = 3; rel = pidx - 16384; }
  const int srcoff[4] = {P_W2A, P_LW1, P_LW2, P_FW1 + 128 * 64};
  const int KBs[4] = {4, 2, 2, 4};
  int j = rel & 7, lane = (rel >> 3) & 63, rest = rel >> 9;
  int kb = rest % KBs[seg], nt = rest / KBs[seg];
  int k = kb * 32 + (lane >> 4) * 8 + j;
  int n = nt * 16 + (lane & 15);
  bp[pidx] = f2b(P[srcoff[seg] + k * 64 + n]);
}

// ---------------- in-degree (u32 atomics) ----------------
__global__ void k_deg(const int* __restrict__ edge, u32* __restrict__ deg) {
  int e = blockIdx.x * 256 + threadIdx.x;
  if (e >= N_EDGES) return;
  atomicAdd(&deg[edge[N_EDGES + e]], 1u);
}

// ---------------- CSR build: scan of deg ----------------
__global__ void k_scan1(const u32* __restrict__ deg, u32* __restrict__ row_ptr,
                        u32* __restrict__ bsum) {
  __shared__ u32 l[256];
  int tid = threadIdx.x;
  int i = blockIdx.x * 256 + tid;
  u32 v = (i < N_NODES) ? deg[i] : 0u;
  l[tid] = v;
  __syncthreads();
  for (int off = 1; off < 256; off <<= 1) {
    u32 a = (tid >= off) ? l[tid - off] : 0u;
    __syncthreads();
    l[tid] += a;
    __syncthreads();
  }
  if (i < N_NODES) row_ptr[i] = l[tid] - v;  // within-block exclusive
  if (tid == 255) bsum[blockIdx.x] = l[255];
}

#define NBLK_SCAN 391

__global__ void k_scan2(u32* __restrict__ bsum) {
  __shared__ u32 l[512];
  int tid = threadIdx.x;
  u32 v = (tid < NBLK_SCAN) ? bsum[tid] : 0u;
  l[tid] = v;
  __syncthreads();
  for (int off = 1; off < 512; off <<= 1) {
    u32 a = (tid >= off) ? l[tid - off] : 0u;
    __syncthreads();
    l[tid] += a;
    __syncthreads();
  }
  if (tid < NBLK_SCAN) bsum[tid] = l[tid] - v;  // exclusive block offsets
}

// ---------------- CSR fill: single packed u32 scatter ----------------
// einfo = src(17b) << 11 | ndeg(7b) << 4 | nlab(4b)
__global__ void k_fill(const int* __restrict__ edge, const int* __restrict__ ndeg,
                       const int* __restrict__ nlab, u32* __restrict__ rp,
                       const u32* __restrict__ bsum, u32* __restrict__ einfo) {
  int e = blockIdx.x * 256 + threadIdx.x;
  if (e >= N_EDGES) return;
  int s = edge[e], d = edge[N_EDGES + e];
  u32 pos = atomicAdd(&rp[d], 1u) + bsum[d >> 8];
  einfo[pos] = ((u32)s << 11) | ((u32)ndeg[s] << 4) | (u32)nlab[s];
}

__device__ __forceinline__ u32 row_start(const u32* rp, const u32* bsum, int n) {
  return (n == 0) ? 0u : rp[n - 1] + bsum[(n - 1) >> 8];
}
__device__ __forceinline__ u32 row_end(const u32* rp, const u32* bsum, int n) {
  return rp[n] + bsum[n >> 8];  // rp[n] was bumped by deg(n) during fill
}

// ---------------- layer-0 aggregation: bf16 LDS W1p, 4-deep pipelined ----------------
__global__ __launch_bounds__(256) void k_agg0(const u32* __restrict__ rp,
                                              const u32* __restrict__ bsum,
                                              const u32* __restrict__ einfo,
                                              const int* __restrict__ ndeg,
                                              const int* __restrict__ nlab,
                                              const float* __restrict__ W1p,
                                              const float* __restrict__ P,
                                              u16* __restrict__ hmid) {
  __shared__ u32 w[NCLS * 64];  // packed bf16 pairs, 20736 B
  for (int i = threadIdx.x; i < NCLS * 64; i += 256) {
    float2 v = ((const float2*)W1p)[i];
    w[i] = pk2(v.x, v.y);
  }
  __syncthreads();
  int lane = threadIdx.x & 63, wv = threadIdx.x >> 6;
  float onep = 1.f + P[P_EPS0];
  float2 b1v = ((const float2*)(P + P_B1A))[lane];
#pragma unroll 1
  for (int it = 0; it < 16; ++it) {
    int n = blockIdx.x * 64 + it * 4 + wv;
    if (n >= N_NODES) continue;
    int dn = ndeg[n], ln = 65 + nlab[n];
    float x0, x1, y0, y1;
    up2(w[dn * 64 + lane], x0, x1);
    up2(w[ln * 64 + lane], y0, y1);
    float s00 = b1v.x + onep * (x0 + y0), s01 = b1v.y + onep * (x1 + y1);
    float s10 = 0.f, s11 = 0.f, s20 = 0.f, s21 = 0.f, s30 = 0.f, s31 = 0.f;
    u32 rb = row_start(rp, bsum, n), re = row_end(rp, bsum, n);
    for (u32 base = rb; base < re; base += 64) {
      u32 m = re - base; if (m > 64u) m = 64u;
      u32 myc = ((u32)lane < m) ? einfo[base + lane] : 0u;
      u32 kk = 0;
      for (; kk + 4 <= m; kk += 4) {
        u32 q0 = (u32)__builtin_amdgcn_readlane((int)myc, (int)kk);
        u32 q1 = (u32)__builtin_amdgcn_readlane((int)myc, (int)(kk + 1));
        u32 q2 = (u32)__builtin_amdgcn_readlane((int)myc, (int)(kk + 2));
        u32 q3 = (u32)__builtin_amdgcn_readlane((int)myc, (int)(kk + 3));
        u32 A0 = w[((q0 >> 4) & 0x7Fu) * 64 + lane], B0 = w[(65u + (q0 & 15u)) * 64 + lane];
        u32 A1 = w[((q1 >> 4) & 0x7Fu) * 64 + lane], B1 = w[(65u + (q1 & 15u)) * 64 + lane];
        u32 A2 = w[((q2 >> 4) & 0x7Fu) * 64 + lane], B2 = w[(65u + (q2 & 15u)) * 64 + lane];
        u32 A3 = w[((q3 >> 4) & 0x7Fu) * 64 + lane], B3 = w[(65u + (q3 & 15u)) * 64 + lane];
        float t0, t1;
        up2(A0, t0, t1); s00 += t0; s01 += t1;
        up2(B0, t0, t1); s00 += t0; s01 += t1;
        up2(A1, t0, t1); s10 += t0; s11 += t1;
        up2(B1, t0, t1); s10 += t0; s11 += t1;
        up2(A2, t0, t1); s20 += t0; s21 += t1;
        up2(B2, t0, t1); s20 += t0; s21 += t1;
        up2(A3, t0, t1); s30 += t0; s31 += t1;
        up2(B3, t0, t1); s30 += t0; s31 += t1;
      }
      for (; kk < m; ++kk) {
        u32 q0 = (u32)__builtin_amdgcn_readlane((int)myc, (int)kk);
        u32 A0 = w[((q0 >> 4) & 0x7Fu) * 64 + lane], B0 = w[(65u + (q0 & 15u)) * 64 + lane];
        float t0, t1;
        up2(A0, t0, t1); s00 += t0; s01 += t1;
        up2(B0, t0, t1); s00 += t0; s01 += t1;
      }
    }
    float a0 = (s00 + s10) + (s20 + s30);
    float a1 = (s01 + s11) + (s21 + s31);
    ((u32*)hmid)[(size_t)n * 64 + lane] = pk2(lrelu(a0), lrelu(a1));
  }
}

// ---------------- MFMA GEMM: C[100k,64] = A[100k,K] @ B + (bias) ----------------
template <int KB, int LDA, int BIASOFF>
__global__ __launch_bounds__(256) void k_gemm(const u16* __restrict__ A,
                                              const u16* __restrict__ Bp,
                                              const float* __restrict__ P,
                                              u16* __restrict__ C) {
  int wid = threadIdx.x >> 6, lane = threadIdx.x & 63;
  int m0 = (blockIdx.x * 4 + wid) * 16;
  if (m0 >= N_NODES) return;
  int row = lane & 15, q = lane >> 4;
  const u16* ap = A + (size_t)(m0 + row) * LDA + q * 8;
  const bf16x8* bp = (const bf16x8*)Bp;
  f32x4 acc[4];
#pragma unroll
  for (int nt = 0; nt < 4; ++nt) {
    float b = (BIASOFF >= 0) ? P[BIASOFF + nt * 16 + row] : 0.f;
    acc[nt][0] = b; acc[nt][1] = b; acc[nt][2] = b; acc[nt][3] = b;
  }
#pragma unroll
  for (int kb = 0; kb < KB; ++kb) {
    bf16x8 af = *(const bf16x8*)(ap + kb * 32);
#pragma unroll
    for (int nt = 0; nt < 4; ++nt) {
      bf16x8 bf = bp[(nt * KB + kb) * 64 + lane];
      acc[nt] = __builtin_amdgcn_mfma_f32_16x16x32_bf16(af, bf, acc[nt], 0, 0, 0);
    }
  }
#pragma unroll
  for (int nt = 0; nt < 4; ++nt)
#pragma unroll
    for (int r = 0; r < 4; ++r) {
      int m = m0 + q * 4 + r;
      C[(size_t)m * 64 + nt * 16 + row] = f2b(acc[nt][r]);
    }
}

// fc1 variant: + Efc[dn]+Efc[ln] row add in epilogue
__global__ __launch_bounds__(256) void k_gemm_fc1(const u16* __restrict__ A,
                                                  const u16* __restrict__ Bp,
                                                  const float* __restrict__ P,
                                                  const int* __restrict__ ndeg,
                                                  const int* __restrict__ nlab,
                                                  const float* __restrict__ Efc,
                                                  u16* __restrict__ C) {
  const int KB = 4, LDA = 128;
  int wid = threadIdx.x >> 6, lane = threadIdx.x & 63;
  int m0 = (blockIdx.x * 4 + wid) * 16;
  if (m0 >= N_NODES) return;
  int row = lane & 15, q = lane >> 4;
  const u16* ap = A + (size_t)(m0 + row) * LDA + q * 8;
  const bf16x8* bp = (const bf16x8*)Bp;
  f32x4 acc[4];
#pragma unroll
  for (int nt = 0; nt < 4; ++nt) {
    float b = P[P_FB1 + nt * 16 + row];
    acc[nt][0] = b; acc[nt][1] = b; acc[nt][2] = b; acc[nt][3] = b;
  }
#pragma unroll
  for (int kb = 0; kb < KB; ++kb) {
    bf16x8 af = *(const bf16x8*)(ap + kb * 32);
#pragma unroll
    for (int nt = 0; nt < 4; ++nt) {
      bf16x8 bf = bp[(nt * KB + kb) * 64 + lane];
      acc[nt] = __builtin_amdgcn_mfma_f32_16x16x32_bf16(af, bf, acc[nt], 0, 0, 0);
    }
  }
#pragma unroll
  for (int r = 0; r < 4; ++r) {
    int m = m0 + q * 4 + r;
    int dn = ndeg[m], ln = 65 + nlab[m];
#pragma unroll
    for (int nt = 0; nt < 4; ++nt) {
      int cc = nt * 16 + row;
      float v = acc[nt][r] + Efc[dn * 64 + cc] + Efc[ln * 64 + cc];
      C[(size_t)m * 64 + cc] = f2b(v);
    }
  }
}

// ---------------- layer-1 aggregation: flat gather, 8-deep, 2 acc chains ----------
__global__ __launch_bounds__(256) void k_agg1(const u32* __restrict__ rp,
                                              const u32* __restrict__ bsum,
                                              const u32* __restrict__ einfo,
                                              const u16* __restrict__ g1,
                                              const float* __restrict__ P,
                                              u16* __restrict__ abuf) {
  int lane = threadIdx.x & 63, wv = threadIdx.x >> 6;
  int n = blockIdx.x * 4 + wv;
  if (n >= N_NODES) return;
  u32 st = row_start(rp, bsum, n), en = row_end(rp, bsum, n);
  u32 m = en - st;
  float acA = 0.f, acB = 0.f;
  u32 k = 0;
  for (; k + 8 <= m; k += 8) {
    u32 c0 = einfo[st + k] >> 11, c1 = einfo[st + k + 1] >> 11;
    u32 c2 = einfo[st + k + 2] >> 11, c3 = einfo[st + k + 3] >> 11;
    u32 c4 = einfo[st + k + 4] >> 11, c5 = einfo[st + k + 5] >> 11;
    u32 c6 = einfo[st + k + 6] >> 11, c7 = einfo[st + k + 7] >> 11;
    float v0 = b2f(g1[(size_t)c0 * 64 + lane]);
    float v1 = b2f(g1[(size_t)c1 * 64 + lane]);
    float v2 = b2f(g1[(size_t)c2 * 64 + lane]);
    float v3 = b2f(g1[(size_t)c3 * 64 + lane]);
    float v4 = b2f(g1[(size_t)c4 * 64 + lane]);
    float v5 = b2f(g1[(size_t)c5 * 64 + lane]);
    float v6 = b2f(g1[(size_t)c6 * 64 + lane]);
    float v7 = b2f(g1[(size_t)c7 * 64 + lane]);
    acA += (v0 + v1) + (v2 + v3);
    acB += (v4 + v5) + (v6 + v7);
  }
  if (k + 4 <= m) {
    u32 c0 = einfo[st + k] >> 11, c1 = einfo[st + k + 1] >> 11;
    u32 c2 = einfo[st + k + 2] >> 11, c3 = einfo[st + k + 3] >> 11;
    float v0 = b2f(g1[(size_t)c0 * 64 + lane]);
    float v1 = b2f(g1[(size_t)c1 * 64 + lane]);
    float v2 = b2f(g1[(size_t)c2 * 64 + lane]);
    float v3 = b2f(g1[(size_t)c3 * 64 + lane]);
    acA += (v0 + v1) + (v2 + v3);
    k += 4;
  }
  for (; k < m; ++k) acB += b2f(g1[(size_t)(einfo[st + k] >> 11) * 64 + lane]);
  float acc = acA + acB;
  float onep = 1.f + P[P_EPS1];
  float a = P[P_LB1 + lane] + fmaf(onep, b2f(g1[(size_t)n * 64 + lane]), acc);
  abuf[(size_t)n * 64 + lane] = f2b(lrelu(a));
}

// ---------------- BatchNorm stats over bf16 t ----------------
__global__ void k_bnstats(const u16* __restrict__ t, float* __restrict__ stats) {
  __shared__ float ls[256], lq[256];
  int tid = threadIdx.x;
  int f = tid & 63, rg = tid >> 6;
  float s = 0.f, q = 0.f;
  for (int n = blockIdx.x * 4 + rg; n < N_NODES; n += gridDim.x * 4) {
    float v = b2f(t[(size_t)n * 64 + f]);
    s += v;
    q = fmaf(v, v, q);
  }
  ls[tid] = s; lq[tid] = q;
  __syncthreads();
  if (tid < 64) {
    s = ls[tid] + ls[tid + 64] + ls[tid + 128] + ls[tid + 192];
    q = lq[tid] + lq[tid + 64] + lq[tid + 128] + lq[tid + 192];
    atomicAdd(&stats[f], s);
    atomicAdd(&stats[64 + f], q);
  }
}

// ---------------- BN finalize + lrelu -> h12 (stride 128, offset dof) ----------------
__global__ void k_bnfin(const u16* __restrict__ t, const float* __restrict__ stats,
                        const float* __restrict__ P, int goff, int boff,
                        u16* __restrict__ h, int dof) {
  int idx = blockIdx.x * blockDim.x + threadIdx.x;
  if (idx >= N_NODES * 64) return;
  int f = idx & 63, n = idx >> 6;
  const float invN = 1.f / (float)N_NODES;
  float m = stats[f] * invN;
  float var = fmaxf(stats[64 + f] * invN - m * m, 0.f);
  float inv = rsqrtf(var + 1e-5f);
  float v = (b2f(t[idx]) - m) * inv * P[goff + f] + P[boff + f];
  v = lrelu(v);
  if (!(fabsf(v) < 1e30f)) v = 999.0f;
  h[(size_t)n * 128 + dof + f] = f2b(v);
}

// ---------------- FC final: BN + lrelu + dot + sigmoid ----------------
__global__ void k_fc2(const u16* __restrict__ t, const float* __restrict__ stats,
                      const float* __restrict__ P, const u32* __restrict__ flag,
                      void* __restrict__ out) {
  int n = blockIdx.x * blockDim.x + threadIdx.x;
  if (n >= N_NODES) return;
  float z = P[P_FB2];
  const float invN = 1.f / (float)N_NODES;
  const u16* tn = t + (size_t)n * 64;
#pragma unroll 1
  for (int f = 0; f < 64; ++f) {
    float m = stats[f] * invN;
    float var = fmaxf(stats[64 + f] * invN - m * m, 0.f);
    float inv = rsqrtf(var + 1e-5f);
    float y = (b2f(tn[f]) - m) * inv * P[P_FG + f] + P[P_FBB + f];
    y = lrelu(y);
    z = fmaf(y, P[P_FW2 + f], z);
  }
  float s = 1.f / (1.f + expf(-z));
  if (!(fabsf(z) < 1e30f)) s = 0.25f;
  if (*flag) ((float*)out)[n] = s;
  else       ((u16*)out)[n] = f2b(s);
}

extern "C" void kernel_launch(void* const* d_in, const int* in_sizes, int n_in,
                              void* d_out, int out_size, void* d_ws, size_t ws_size,
                              hipStream_t stream) {
  const int* node_deg = (const int*)d_in[0];
  const int* node_lab = (const int*)d_in[1];
  const int* edge     = (const int*)d_in[2];
  (void)in_sizes; (void)n_in; (void)out_size; (void)ws_size;

  char* base = (char*)d_ws;
  size_t off = 0;
  auto alloc = [&](size_t bytes) -> void* {
    void* p = base + off;
    off += (bytes + 15) & ~(size_t)15;
    return p;
  };
  float* Pb    = (float*)alloc((size_t)P_TOT * 4);
  // contiguous zero region: flag | stats | deg  (one memset)
  u32* flag    = (u32*)alloc(16);
  float* stats = (float*)alloc(384 * 4);
  u32* deg     = (u32*)alloc((size_t)N_NODES * 4);
  float* W1p   = (float*)alloc(NCLS * 128 * 4);
  float* Efc   = (float*)alloc(NCLS * 64 * 4);
  u16* bpack   = (u16*)alloc(24576 * 2);
  u32* row_ptr = (u32*)alloc((size_t)(N_NODES + 1) * 4);
  u32* bsum    = (u32*)alloc(512 * 4);
  u32* einfo   = (u32*)alloc((size_t)N_EDGES * 4);
  void* arena  = alloc((size_t)N_NODES * 128 * 2);  // hmid; later g1+abuf
  u16* h12     = (u16*)alloc((size_t)N_NODES * 128 * 2);
  u16* t       = (u16*)alloc((size_t)N_NODES * 64 * 2);
  u16* hmid = (u16*)arena;
  u16* g1   = (u16*)arena;
  u16* abuf = (u16*)arena + (size_t)N_NODES * 64;
  u16* Bp_w2a = bpack;           // 8192
  u16* Bp_lw1 = bpack + 8192;    // 4096
  u16* Bp_lw2 = bpack + 12288;   // 4096
  u16* Bp_fw1 = bpack + 16384;   // 8192

  hipMemsetAsync(flag, 0, 16 + 384 * 4 + (size_t)N_NODES * 4, stream);

  k_detect<<<1, 256, 0, stream>>>((const u16*)d_in[3], flag);

  CvtAll ca;
  const int srcidx[22] = {3, 4, 5, 6, 7, 8, 9, 10, 11, 12, 13, 14, 15, 16, 17, 18, 19, 20, 21, 22, 23, 24};
  const int cnts[22]   = {4160, 1024, 16384, 128, 8192, 64, 1, 64, 64, 4096, 64, 4096, 64, 1, 64, 64, 16384, 64, 64, 64, 64, 1};
  const int offs[22]   = {P_EMBD, P_EMBL, P_W1A, P_B1A, P_W2A, P_B2A, P_EPS0, P_G0, P_BB0,
                          P_LW1, P_LB1, P_LW2, P_LB2, P_EPS1, P_G1, P_BB1,
                          P_FW1, P_FB1, P_FG, P_FBB, P_FW2, P_FB2};
  for (int i = 0; i < 22; ++i) { ca.src[i] = d_in[srcidx[i]]; ca.cnt[i] = cnts[i]; ca.off[i] = offs[i]; }
  k_cvtall<<<dim3(64, 22), 256, 0, stream>>>(ca, flag, Pb);

  k_prep<<<157, 256, 0, stream>>>(Pb, W1p, Efc, bpack);

  // CSR build (no scan3/cursor: fill bumps row_ptr, consumers add bsum)
  k_deg<<<(N_EDGES + 255) / 256, 256, 0, stream>>>(edge, deg);
  k_scan1<<<NBLK_SCAN, 256, 0, stream>>>(deg, row_ptr, bsum);
  k_scan2<<<1, 512, 0, stream>>>(bsum);
  k_fill<<<(N_EDGES + 255) / 256, 256, 0, stream>>>(edge, node_deg, node_lab, row_ptr, bsum, einfo);

  const int GEMM_GRID = (6250 + 3) / 4;

  // layer 0
  k_agg0<<<(N_NODES + 63) / 64, 256, 0, stream>>>(row_ptr, bsum, einfo, node_deg, node_lab, W1p, Pb, hmid);
  k_gemm<4, 128, P_B2A><<<GEMM_GRID, 256, 0, stream>>>(hmid, Bp_w2a, Pb, t);
  k_bnstats<<<512, 256, 0, stream>>>(t, stats);
  k_bnfin<<<(N_NODES * 64 + 255) / 256, 256, 0, stream>>>(t, stats, Pb, P_G0, P_BB0, h12, 0);

  // layer 1: GEMM-first, flat gather aggregation, GEMM
  k_gemm<2, 128, -1><<<GEMM_GRID, 256, 0, stream>>>(h12, Bp_lw1, Pb, g1);
  k_agg1<<<(N_NODES + 3) / 4, 256, 0, stream>>>(row_ptr, bsum, einfo, g1, Pb, abuf);
  k_gemm<2, 64, P_LB2><<<GEMM_GRID, 256, 0, stream>>>(abuf, Bp_lw2, Pb, t);
  k_bnstats<<<512, 256, 0, stream>>>(t, stats + 128);
  k_bnfin<<<(N_NODES * 64 + 255) / 256, 256, 0, stream>>>(t, stats + 128, Pb, P_G1, P_BB1, h12, 64);

  // FC head
  k_gemm_fc1<<<GEMM_GRID, 256, 0, stream>>>(h12, Bp_fw1, Pb, node_deg, node_lab, Efc, t);
  k_bnstats<<<512, 256, 0, stream>>>(t, stats + 256);
  k_fc2<<<(N_NODES + 255) / 256, 256, 0, stream>>>(t, stats + 256, Pb, flag, d_out);
}

// Round 10
// 496.004 us; speedup vs baseline: 1.2034x; 1.0399x over previous
//
#include <hip/hip_runtime.h>

#define N_NODES 100000
#define N_EDGES 1200000
#define NCLS 81   // 65 deg classes + 16 lab classes
#define NBKT 196  // dst>>9 buckets (512 nodes each)
#define NCHK 293  // ceil(N_EDGES/4096)

typedef unsigned short u16;
typedef unsigned int u32;
typedef unsigned long long u64;
typedef short bf16x8 __attribute__((ext_vector_type(8)));
typedef float f32x4 __attribute__((ext_vector_type(4)));

__device__ __forceinline__ float b2f(u16 u) {
  union { u32 i; float f; } v; v.i = ((u32)u) << 16; return v.f;
}
__device__ __forceinline__ u16 f2b(float f) {
  union { float f; u32 i; } v; v.f = f;
  u32 x = v.i;
  return (u16)((x + 0x7fffu + ((x >> 16) & 1u)) >> 16);
}
__device__ __forceinline__ u32 pk2(float lo, float hi) {
  return (u32)f2b(lo) | ((u32)f2b(hi) << 16);
}
__device__ __forceinline__ void up2(u32 w, float& lo, float& hi) {
  union { u32 u; float f; } a, b;
  a.u = w << 16; b.u = w & 0xffff0000u;
  lo = a.f; hi = b.f;
}
__device__ __forceinline__ float lrelu(float x) { return x > 0.f ? x : 0.01f * x; }

// ---- fp32 param block offsets ----
#define P_EMBD 0       // 4160
#define P_EMBL 4160    // 1024
#define P_W1A  5184    // 16384  l0_w1 (128x128)
#define P_B1A  21568   // 128
#define P_W2A  21696   // 8192   l0_w2 (128x64)
#define P_B2A  29888   // 64
#define P_EPS0 29952   // 1
#define P_G0   29953   // 64
#define P_BB0  30017   // 64
#define P_LW1  30081   // 4096   l1_w1 (64x64)
#define P_LB1  34177   // 64
#define P_LW2  34241   // 4096   l1_w2 (64x64)
#define P_LB2  38337   // 64
#define P_EPS1 38401   // 1
#define P_G1   38402   // 64
#define P_BB1  38466   // 64
#define P_FW1  38530   // 16384  fc_w1 (256x64)
#define P_FB1  54914   // 64
#define P_FG   54978   // 64
#define P_FBB  55042   // 64
#define P_FW2  55106   // 64
#define P_FB2  55170   // 1
#define P_TOT  55171

// ---------------- dtype detection ----------------
__global__ void k_detect(const u16* __restrict__ e, u32* __restrict__ flag) {
  u32 t = 0;
  for (int k = threadIdx.x; k < 4096; k += 256) {
    u32 ex = (e[k] >> 7) & 0xFF;
    if (ex >= 0x90) t = 1;
  }
  if (t) atomicOr(flag, 1u);
}

// ---------------- convert all float params to fp32 block ----------------
struct CvtAll {
  const void* src[22];
  int cnt[22];
  int off[22];
};

__global__ void k_cvtall(CvtAll a, const u32* __restrict__ flag, float* __restrict__ P) {
  int seg = blockIdx.y;
  int i = blockIdx.x * 256 + threadIdx.x;
  if (i >= a.cnt[seg]) return;
  float v;
  if (*flag) v = ((const float*)a.src[seg])[i];
  else       v = b2f(((const u16*)a.src[seg])[i]);
  P[a.off[seg] + i] = v;
}

// ---------------- merged preprocessing: W1p, Efc, MFMA B-pack ----------------
__global__ void k_prep(const float* __restrict__ P, float* __restrict__ W1p,
                       float* __restrict__ Efc, u16* __restrict__ bp) {
  int idx = blockIdx.x * 256 + threadIdx.x;
  if (idx < NCLS * 128) {
    int c = idx >> 7, h = idx & 127;
    const float* w1 = P + P_W1A;
    float s = 0.f;
    if (c < 65) {
      const float* em = P + P_EMBD + c * 64;
      for (int k = 0; k < 64; ++k) s = fmaf(em[k], w1[k * 128 + h], s);
    } else {
      const float* em = P + P_EMBL + (c - 65) * 64;
      for (int k = 0; k < 64; ++k) s = fmaf(em[k], w1[(64 + k) * 128 + h], s);
    }
    W1p[idx] = s;
    return;
  }
  if (idx < NCLS * 128 + NCLS * 64) {
    int r = idx - NCLS * 128;
    int c = r >> 6, o = r & 63;
    const float* fw = P + P_FW1;
    float s = 0.f;
    if (c < 65) {
      const float* em = P + P_EMBD + c * 64;
      for (int k = 0; k < 64; ++k) s = fmaf(em[k], fw[k * 64 + o], s);
    } else {
      const float* em = P + P_EMBL + (c - 65) * 64;
      for (int k = 0; k < 64; ++k) s = fmaf(em[k], fw[(64 + k) * 64 + o], s);
    }
    Efc[r] = s;
    return;
  }
  int pidx = idx - (NCLS * 128 + NCLS * 64);
  if (pidx >= 24576) return;
  int seg, rel;
  if (pidx < 8192)       { seg = 0; rel = pidx; }
  else if (pidx < 12288) { seg = 1; rel = pidx - 8192; }
  else if (pidx < 16384) { seg = 2; rel = pidx - 12288; }
  else                   { seg = 3; rel = pidx - 16384; }
  const int srcoff[4] = {P_W2A, P_LW1, P_LW2, P_FW1 + 128 * 64};
  const int KBs[4] = {4, 2, 2, 4};
  int j = rel & 7, lane = (rel >> 3) & 63, rest = rel >> 9;
  int kb = rest % KBs[seg], nt = rest / KBs[seg];
  int k = kb * 32 + (lane >> 4) * 8 + j;
  int n = nt * 16 + (lane & 15);
  bp[pidx] = f2b(P[srcoff[seg] + k * 64 + n]);
}

// ---------------- bucket counting-sort of edges by dst>>9 ----------------
__global__ __launch_bounds__(256) void k_bc(const int* __restrict__ edge, u32* __restrict__ tcnt) {
  __shared__ u32 c[NBKT];
  for (int i = threadIdx.x; i < NBKT; i += 256) c[i] = 0;
  __syncthreads();
  int base = blockIdx.x * 4096;
  for (int i = threadIdx.x; i < 4096; i += 256) {
    int e = base + i;
    if (e < N_EDGES) atomicAdd(&c[(u32)edge[N_EDGES + e] >> 9], 1u);
  }
  __syncthreads();
  for (int i = threadIdx.x; i < NBKT; i += 256)
    if (c[i]) atomicAdd(&tcnt[i], c[i]);
}

__global__ void k_bscan(const u32* __restrict__ tcnt, u32* __restrict__ gcur) {
  __shared__ u32 l[256];
  int tid = threadIdx.x;
  u32 v = (tid < NBKT) ? tcnt[tid] : 0u;
  l[tid] = v;
  __syncthreads();
  for (int off = 1; off < 256; off <<= 1) {
    u32 a = (tid >= off) ? l[tid - off] : 0u;
    __syncthreads();
    l[tid] += a;
    __syncthreads();
  }
  if (tid < NBKT) gcur[tid] = l[tid] - v;  // exclusive bucket bases
}

// phase 2: stage 4096 edges in LDS, claim contiguous per-bucket runs, write grouped
__global__ __launch_bounds__(256) void k_bsort(const int* __restrict__ edge,
                                               const int* __restrict__ ndeg,
                                               const int* __restrict__ nlab,
                                               u32* __restrict__ gcur,
                                               u64* __restrict__ e2) {
  __shared__ u32 cnt[NBKT], rbase[NBKT];
  __shared__ u32 slo[4096], shi[4096];
  for (int i = threadIdx.x; i < NBKT; i += 256) cnt[i] = 0;
  __syncthreads();
  int base = blockIdx.x * 4096;
  for (int i = threadIdx.x; i < 4096; i += 256) {
    int e = base + i;
    if (e < N_EDGES) {
      int s = edge[e], d = edge[N_EDGES + e];
      slo[i] = ((u32)s << 11) | ((u32)ndeg[s] << 4) | (u32)nlab[s];
      shi[i] = (u32)d;
      atomicAdd(&cnt[(u32)d >> 9], 1u);
    } else shi[i] = 0xFFFFFFFFu;
  }
  __syncthreads();
  for (int i = threadIdx.x; i < NBKT; i += 256) {
    u32 c = cnt[i];
    rbase[i] = c ? atomicAdd(&gcur[i], c) : 0u;
    cnt[i] = 0;  // reuse as local rank
  }
  __syncthreads();
  for (int i = threadIdx.x; i < 4096; i += 256) {
    u32 d = shi[i];
    if (d == 0xFFFFFFFFu) continue;
    u32 b = d >> 9;
    u32 pos = rbase[b] + atomicAdd(&cnt[b], 1u);
    e2[pos] = ((u64)d << 32) | (u64)slo[i];
  }
}

// ---------------- in-degree over dst-sorted edges (bucket-local atomics) ----------
__global__ void k_deg2(const u64* __restrict__ e2, u32* __restrict__ deg) {
  int e = blockIdx.x * 256 + threadIdx.x;
  if (e >= N_EDGES) return;
  atomicAdd(&deg[(u32)(e2[e] >> 32)], 1u);
}

// ---------------- CSR scan ----------------
__global__ void k_scan1(const u32* __restrict__ deg, u32* __restrict__ row_ptr,
                        u32* __restrict__ bsum) {
  __shared__ u32 l[256];
  int tid = threadIdx.x;
  int i = blockIdx.x * 256 + tid;
  u32 v = (i < N_NODES) ? deg[i] : 0u;
  l[tid] = v;
  __syncthreads();
  for (int off = 1; off < 256; off <<= 1) {
    u32 a = (tid >= off) ? l[tid - off] : 0u;
    __syncthreads();
    l[tid] += a;
    __syncthreads();
  }
  if (i < N_NODES) row_ptr[i] = l[tid] - v;
  if (tid == 255) bsum[blockIdx.x] = l[255];
}

#define NBLK_SCAN 391

__global__ void k_scan2(u32* __restrict__ bsum) {
  __shared__ u32 l[512];
  int tid = threadIdx.x;
  u32 v = (tid < NBLK_SCAN) ? bsum[tid] : 0u;
  l[tid] = v;
  __syncthreads();
  for (int off = 1; off < 512; off <<= 1) {
    u32 a = (tid >= off) ? l[tid - off] : 0u;
    __syncthreads();
    l[tid] += a;
    __syncthreads();
  }
  if (tid < NBLK_SCAN) bsum[tid] = l[tid] - v;
}

// ---------------- CSR fill from sorted edges (L2-local scatter) ----------------
__global__ void k_fill2(const u64* __restrict__ e2, u32* __restrict__ rp,
                        const u32* __restrict__ bsum, u32* __restrict__ einfo) {
  int e = blockIdx.x * 256 + threadIdx.x;
  if (e >= N_EDGES) return;
  u64 r = e2[e];
  u32 d = (u32)(r >> 32);
  u32 pos = atomicAdd(&rp[d], 1u) + bsum[d >> 8];
  einfo[pos] = (u32)r;
}

__device__ __forceinline__ u32 row_start(const u32* rp, const u32* bsum, int n) {
  return (n == 0) ? 0u : rp[n - 1] + bsum[(n - 1) >> 8];
}
__device__ __forceinline__ u32 row_end(const u32* rp, const u32* bsum, int n) {
  return rp[n] + bsum[n >> 8];
}

// ---------------- layer-0 aggregation: bf16 LDS W1p, 4-deep pipelined ----------------
__global__ __launch_bounds__(256) void k_agg0(const u32* __restrict__ rp,
                                              const u32* __restrict__ bsum,
                                              const u32* __restrict__ einfo,
                                              const int* __restrict__ ndeg,
                                              const int* __restrict__ nlab,
                                              const float* __restrict__ W1p,
                                              const float* __restrict__ P,
                                              u16* __restrict__ hmid) {
  __shared__ u32 w[NCLS * 64];
  for (int i = threadIdx.x; i < NCLS * 64; i += 256) {
    float2 v = ((const float2*)W1p)[i];
    w[i] = pk2(v.x, v.y);
  }
  __syncthreads();
  int lane = threadIdx.x & 63, wv = threadIdx.x >> 6;
  float onep = 1.f + P[P_EPS0];
  float2 b1v = ((const float2*)(P + P_B1A))[lane];
#pragma unroll 1
  for (int it = 0; it < 16; ++it) {
    int n = blockIdx.x * 64 + it * 4 + wv;
    if (n >= N_NODES) continue;
    int dn = ndeg[n], ln = 65 + nlab[n];
    float x0, x1, y0, y1;
    up2(w[dn * 64 + lane], x0, x1);
    up2(w[ln * 64 + lane], y0, y1);
    float s00 = b1v.x + onep * (x0 + y0), s01 = b1v.y + onep * (x1 + y1);
    float s10 = 0.f, s11 = 0.f, s20 = 0.f, s21 = 0.f, s30 = 0.f, s31 = 0.f;
    u32 rb = row_start(rp, bsum, n), re = row_end(rp, bsum, n);
    for (u32 base = rb; base < re; base += 64) {
      u32 m = re - base; if (m > 64u) m = 64u;
      u32 myc = ((u32)lane < m) ? einfo[base + lane] : 0u;
      u32 kk = 0;
      for (; kk + 4 <= m; kk += 4) {
        u32 q0 = (u32)__builtin_amdgcn_readlane((int)myc, (int)kk);
        u32 q1 = (u32)__builtin_amdgcn_readlane((int)myc, (int)(kk + 1));
        u32 q2 = (u32)__builtin_amdgcn_readlane((int)myc, (int)(kk + 2));
        u32 q3 = (u32)__builtin_amdgcn_readlane((int)myc, (int)(kk + 3));
        u32 A0 = w[((q0 >> 4) & 0x7Fu) * 64 + lane], B0 = w[(65u + (q0 & 15u)) * 64 + lane];
        u32 A1 = w[((q1 >> 4) & 0x7Fu) * 64 + lane], B1 = w[(65u + (q1 & 15u)) * 64 + lane];
        u32 A2 = w[((q2 >> 4) & 0x7Fu) * 64 + lane], B2 = w[(65u + (q2 & 15u)) * 64 + lane];
        u32 A3 = w[((q3 >> 4) & 0x7Fu) * 64 + lane], B3 = w[(65u + (q3 & 15u)) * 64 + lane];
        float t0, t1;
        up2(A0, t0, t1); s00 += t0; s01 += t1;
        up2(B0, t0, t1); s00 += t0; s01 += t1;
        up2(A1, t0, t1); s10 += t0; s11 += t1;
        up2(B1, t0, t1); s10 += t0; s11 += t1;
        up2(A2, t0, t1); s20 += t0; s21 += t1;
        up2(B2, t0, t1); s20 += t0; s21 += t1;
        up2(A3, t0, t1); s30 += t0; s31 += t1;
        up2(B3, t0, t1); s30 += t0; s31 += t1;
      }
      for (; kk < m; ++kk) {
        u32 q0 = (u32)__builtin_amdgcn_readlane((int)myc, (int)kk);
        u32 A0 = w[((q0 >> 4) & 0x7Fu) * 64 + lane], B0 = w[(65u + (q0 & 15u)) * 64 + lane];
        float t0, t1;
        up2(A0, t0, t1); s00 += t0; s01 += t1;
        up2(B0, t0, t1); s00 += t0; s01 += t1;
      }
    }
    float a0 = (s00 + s10) + (s20 + s30);
    float a1 = (s01 + s11) + (s21 + s31);
    ((u32*)hmid)[(size_t)n * 64 + lane] = pk2(lrelu(a0), lrelu(a1));
  }
}

// ---------------- MFMA GEMM (plain): C = A @ B + bias ----------------
template <int KB, int LDA, int BIASOFF>
__global__ __launch_bounds__(256) void k_gemm(const u16* __restrict__ A,
                                              const u16* __restrict__ Bp,
                                              const float* __restrict__ P,
                                              u16* __restrict__ C) {
  int wid = threadIdx.x >> 6, lane = threadIdx.x & 63;
  int m0 = (blockIdx.x * 4 + wid) * 16;
  if (m0 >= N_NODES) return;
  int row = lane & 15, q = lane >> 4;
  const u16* ap = A + (size_t)(m0 + row) * LDA + q * 8;
  const bf16x8* bp = (const bf16x8*)Bp;
  f32x4 acc[4];
#pragma unroll
  for (int nt = 0; nt < 4; ++nt) {
    float b = (BIASOFF >= 0) ? P[BIASOFF + nt * 16 + row] : 0.f;
    acc[nt][0] = b; acc[nt][1] = b; acc[nt][2] = b; acc[nt][3] = b;
  }
#pragma unroll
  for (int kb = 0; kb < KB; ++kb) {
    bf16x8 af = *(const bf16x8*)(ap + kb * 32);
#pragma unroll
    for (int nt = 0; nt < 4; ++nt) {
      bf16x8 bf = bp[(nt * KB + kb) * 64 + lane];
      acc[nt] = __builtin_amdgcn_mfma_f32_16x16x32_bf16(af, bf, acc[nt], 0, 0, 0);
    }
  }
#pragma unroll
  for (int nt = 0; nt < 4; ++nt)
#pragma unroll
    for (int r = 0; r < 4; ++r) {
      int m = m0 + q * 4 + r;
      C[(size_t)m * 64 + nt * 16 + row] = f2b(acc[nt][r]);
    }
}

// ---------------- MFMA GEMM with fused BN+lrelu on A (K=64): g1 = lrelu(BN0(t0)) @ LW1
__global__ __launch_bounds__(256) void k_gemm_bn(const u16* __restrict__ A,
                                                 const u16* __restrict__ Bp,
                                                 const float* __restrict__ P,
                                                 const float* __restrict__ stats,
                                                 u16* __restrict__ C) {
  int wid = threadIdx.x >> 6, lane = threadIdx.x & 63;
  int m0 = (blockIdx.x * 4 + wid) * 16;
  if (m0 >= N_NODES) return;
  int row = lane & 15, q = lane >> 4;
  const float invN = 1.f / (float)N_NODES;
  float sc[16], sh[16];
#pragma unroll
  for (int kb = 0; kb < 2; ++kb)
#pragma unroll
    for (int j = 0; j < 8; ++j) {
      int f = kb * 32 + q * 8 + j;
      float mm = stats[f] * invN;
      float var = fmaxf(stats[64 + f] * invN - mm * mm, 0.f);
      float inv = rsqrtf(var + 1e-5f);
      float s = inv * P[P_G0 + f];
      sc[kb * 8 + j] = s;
      sh[kb * 8 + j] = P[P_BB0 + f] - mm * s;
    }
  const u16* ap = A + (size_t)(m0 + row) * 64 + q * 8;
  const bf16x8* bp = (const bf16x8*)Bp;
  f32x4 acc[4];
#pragma unroll
  for (int nt = 0; nt < 4; ++nt) {
    acc[nt][0] = 0.f; acc[nt][1] = 0.f; acc[nt][2] = 0.f; acc[nt][3] = 0.f;
  }
#pragma unroll
  for (int kb = 0; kb < 2; ++kb) {
    uint4 raw = *(const uint4*)(ap + kb * 32);
    u32 rw[4] = {raw.x, raw.y, raw.z, raw.w};
    bf16x8 af;
#pragma unroll
    for (int p = 0; p < 4; ++p) {
      float lo, hi;
      up2(rw[p], lo, hi);
      float y0 = lrelu(fmaf(sc[kb * 8 + 2 * p], lo, sh[kb * 8 + 2 * p]));
      float y1 = lrelu(fmaf(sc[kb * 8 + 2 * p + 1], hi, sh[kb * 8 + 2 * p + 1]));
      af[2 * p] = (short)f2b(y0);
      af[2 * p + 1] = (short)f2b(y1);
    }
#pragma unroll
    for (int nt = 0; nt < 4; ++nt) {
      bf16x8 bf = bp[(nt * 2 + kb) * 64 + lane];
      acc[nt] = __builtin_amdgcn_mfma_f32_16x16x32_bf16(af, bf, acc[nt], 0, 0, 0);
    }
  }
#pragma unroll
  for (int nt = 0; nt < 4; ++nt)
#pragma unroll
    for (int r = 0; r < 4; ++r) {
      int m = m0 + q * 4 + r;
      C[(size_t)m * 64 + nt * 16 + row] = f2b(acc[nt][r]);
    }
}

// ---------------- fc1 GEMM: A = [BN0(t0) | BN1(t1)] fused, + Efc epilogue ----------
__global__ __launch_bounds__(256) void k_gemm_fc1bn(const u16* __restrict__ t0,
                                                    const u16* __restrict__ t1,
                                                    const u16* __restrict__ Bp,
                                                    const float* __restrict__ P,
                                                    const float* __restrict__ stats,
                                                    const int* __restrict__ ndeg,
                                                    const int* __restrict__ nlab,
                                                    const float* __restrict__ Efc,
                                                    u16* __restrict__ C) {
  int wid = threadIdx.x >> 6, lane = threadIdx.x & 63;
  int m0 = (blockIdx.x * 4 + wid) * 16;
  if (m0 >= N_NODES) return;
  int row = lane & 15, q = lane >> 4;
  const float invN = 1.f / (float)N_NODES;
  float sc[32], sh[32];
#pragma unroll
  for (int h = 0; h < 2; ++h) {
    const float* st = stats + h * 128;
    int gof = h ? P_G1 : P_G0, bof = h ? P_BB1 : P_BB0;
#pragma unroll
    for (int kb = 0; kb < 2; ++kb)
#pragma unroll
      for (int j = 0; j < 8; ++j) {
        int f = kb * 32 + q * 8 + j;
        float mm = st[f] * invN;
        float var = fmaxf(st[64 + f] * invN - mm * mm, 0.f);
        float inv = rsqrtf(var + 1e-5f);
        float s = inv * P[gof + f];
        sc[h * 16 + kb * 8 + j] = s;
        sh[h * 16 + kb * 8 + j] = P[bof + f] - mm * s;
      }
  }
  const u16* a0 = t0 + (size_t)(m0 + row) * 64 + q * 8;
  const u16* a1 = t1 + (size_t)(m0 + row) * 64 + q * 8;
  const bf16x8* bp = (const bf16x8*)Bp;
  f32x4 acc[4];
#pragma unroll
  for (int nt = 0; nt < 4; ++nt) {
    float b = P[P_FB1 + nt * 16 + row];
    acc[nt][0] = b; acc[nt][1] = b; acc[nt][2] = b; acc[nt][3] = b;
  }
#pragma unroll
  for (int kb = 0; kb < 4; ++kb) {
    const u16* src = (kb < 2) ? (a0 + kb * 32) : (a1 + (kb - 2) * 32);
    int ci = (kb < 2) ? kb * 8 : 16 + (kb - 2) * 8;
    uint4 raw = *(const uint4*)src;
    u32 rw[4] = {raw.x, raw.y, raw.z, raw.w};
    bf16x8 af;
#pragma unroll
    for (int p = 0; p < 4; ++p) {
      float lo, hi;
      up2(rw[p], lo, hi);
      float y0 = lrelu(fmaf(sc[ci + 2 * p], lo, sh[ci + 2 * p]));
      float y1 = lrelu(fmaf(sc[ci + 2 * p + 1], hi, sh[ci + 2 * p + 1]));
      af[2 * p] = (short)f2b(y0);
      af[2 * p + 1] = (short)f2b(y1);
    }
#pragma unroll
    for (int nt = 0; nt < 4; ++nt) {
      bf16x8 bf = bp[(nt * 4 + kb) * 64 + lane];
      acc[nt] = __builtin_amdgcn_mfma_f32_16x16x32_bf16(af, bf, acc[nt], 0, 0, 0);
    }
  }
#pragma unroll
  for (int r = 0; r < 4; ++r) {
    int m = m0 + q * 4 + r;
    int dn = ndeg[m], ln = 65 + nlab[m];
#pragma unroll
    for (int nt = 0; nt < 4; ++nt) {
      int cc = nt * 16 + row;
      float v = acc[nt][r] + Efc[dn * 64 + cc] + Efc[ln * 64 + cc];
      C[(size_t)m * 64 + cc] = f2b(v);
    }
  }
}

// ---------------- layer-1 aggregation: flat gather, 8-deep, 2 acc chains ----------
__global__ __launch_bounds__(256) void k_agg1(const u32* __restrict__ rp,
                                              const u32* __restrict__ bsum,
                                              const u32* __restrict__ einfo,
                                              const u16* __restrict__ g1,
                                              const float* __restrict__ P,
                                              u16* __restrict__ abuf) {
  int lane = threadIdx.x & 63, wv = threadIdx.x >> 6;
  int n = blockIdx.x * 4 + wv;
  if (n >= N_NODES) return;
  u32 st = row_start(rp, bsum, n), en = row_end(rp, bsum, n);
  u32 m = en - st;
  float acA = 0.f, acB = 0.f;
  u32 k = 0;
  for (; k + 8 <= m; k += 8) {
    u32 c0 = einfo[st + k] >> 11, c1 = einfo[st + k + 1] >> 11;
    u32 c2 = einfo[st + k + 2] >> 11, c3 = einfo[st + k + 3] >> 11;
    u32 c4 = einfo[st + k + 4] >> 11, c5 = einfo[st + k + 5] >> 11;
    u32 c6 = einfo[st + k + 6] >> 11, c7 = einfo[st + k + 7] >> 11;
    float v0 = b2f(g1[(size_t)c0 * 64 + lane]);
    float v1 = b2f(g1[(size_t)c1 * 64 + lane]);
    float v2 = b2f(g1[(size_t)c2 * 64 + lane]);
    float v3 = b2f(g1[(size_t)c3 * 64 + lane]);
    float v4 = b2f(g1[(size_t)c4 * 64 + lane]);
    float v5 = b2f(g1[(size_t)c5 * 64 + lane]);
    float v6 = b2f(g1[(size_t)c6 * 64 + lane]);
    float v7 = b2f(g1[(size_t)c7 * 64 + lane]);
    acA += (v0 + v1) + (v2 + v3);
    acB += (v4 + v5) + (v6 + v7);
  }
  if (k + 4 <= m) {
    u32 c0 = einfo[st + k] >> 11, c1 = einfo[st + k + 1] >> 11;
    u32 c2 = einfo[st + k + 2] >> 11, c3 = einfo[st + k + 3] >> 11;
    float v0 = b2f(g1[(size_t)c0 * 64 + lane]);
    float v1 = b2f(g1[(size_t)c1 * 64 + lane]);
    float v2 = b2f(g1[(size_t)c2 * 64 + lane]);
    float v3 = b2f(g1[(size_t)c3 * 64 + lane]);
    acA += (v0 + v1) + (v2 + v3);
    k += 4;
  }
  for (; k < m; ++k) acB += b2f(g1[(size_t)(einfo[st + k] >> 11) * 64 + lane]);
  float acc = acA + acB;
  float onep = 1.f + P[P_EPS1];
  float a = P[P_LB1 + lane] + fmaf(onep, b2f(g1[(size_t)n * 64 + lane]), acc);
  abuf[(size_t)n * 64 + lane] = f2b(lrelu(a));
}

// ---------------- BatchNorm stats over bf16 t ----------------
__global__ void k_bnstats(const u16* __restrict__ t, float* __restrict__ stats) {
  __shared__ float ls[256], lq[256];
  int tid = threadIdx.x;
  int f = tid & 63, rg = tid >> 6;
  float s = 0.f, q = 0.f;
  for (int n = blockIdx.x * 4 + rg; n < N_NODES; n += gridDim.x * 4) {
    float v = b2f(t[(size_t)n * 64 + f]);
    s += v;
    q = fmaf(v, v, q);
  }
  ls[tid] = s; lq[tid] = q;
  __syncthreads();
  if (tid < 64) {
    s = ls[tid] + ls[tid + 64] + ls[tid + 128] + ls[tid + 192];
    q = lq[tid] + lq[tid + 64] + lq[tid + 128] + lq[tid + 192];
    atomicAdd(&stats[f], s);
    atomicAdd(&stats[64 + f], q);
  }
}

// ---------------- FC final: BN + lrelu + dot + sigmoid ----------------
__global__ void k_fc2(const u16* __restrict__ t, const float* __restrict__ stats,
                      const float* __restrict__ P, const u32* __restrict__ flag,
                      void* __restrict__ out) {
  int n = blockIdx.x * blockDim.x + threadIdx.x;
  if (n >= N_NODES) return;
  float z = P[P_FB2];
  const float invN = 1.f / (float)N_NODES;
  const u16* tn = t + (size_t)n * 64;
#pragma unroll 1
  for (int f = 0; f < 64; ++f) {
    float m = stats[f] * invN;
    float var = fmaxf(stats[64 + f] * invN - m * m, 0.f);
    float inv = rsqrtf(var + 1e-5f);
    float y = (b2f(tn[f]) - m) * inv * P[P_FG + f] + P[P_FBB + f];
    y = lrelu(y);
    z = fmaf(y, P[P_FW2 + f], z);
  }
  float s = 1.f / (1.f + expf(-z));
  if (!(fabsf(z) < 1e30f)) s = 0.25f;
  if (*flag) ((float*)out)[n] = s;
  else       ((u16*)out)[n] = f2b(s);
}

extern "C" void kernel_launch(void* const* d_in, const int* in_sizes, int n_in,
                              void* d_out, int out_size, void* d_ws, size_t ws_size,
                              hipStream_t stream) {
  const int* node_deg = (const int*)d_in[0];
  const int* node_lab = (const int*)d_in[1];
  const int* edge     = (const int*)d_in[2];
  (void)in_sizes; (void)n_in; (void)out_size; (void)ws_size;

  char* base = (char*)d_ws;
  size_t off = 0;
  auto alloc = [&](size_t bytes) -> void* {
    void* p = base + off;
    off += (bytes + 15) & ~(size_t)15;
    return p;
  };
  float* Pb    = (float*)alloc((size_t)P_TOT * 4);
  // contiguous zero region: flag | stats | deg | tcnt (one memset)
  u32* flag    = (u32*)alloc(16);
  float* stats = (float*)alloc(384 * 4);
  u32* deg     = (u32*)alloc((size_t)N_NODES * 4);
  u32* tcnt    = (u32*)alloc(NBKT * 4);
  float* W1p   = (float*)alloc(NCLS * 128 * 4);
  float* Efc   = (float*)alloc(NCLS * 64 * 4);
  u16* bpack   = (u16*)alloc(24576 * 2);
  u32* row_ptr = (u32*)alloc((size_t)(N_NODES + 1) * 4);
  u32* bsum    = (u32*)alloc(512 * 4);
  u32* gcur    = (u32*)alloc(NBKT * 4);
  u32* einfo   = (u32*)alloc((size_t)N_EDGES * 4);
  u64* e2      = (u64*)alloc((size_t)N_EDGES * 8);
  void* arena  = alloc((size_t)N_NODES * 128 * 2);  // hmid; later g1+abuf
  u16* t0      = (u16*)alloc((size_t)N_NODES * 64 * 2);
  u16* t1      = (u16*)alloc((size_t)N_NODES * 64 * 2);
  u16* t2      = (u16*)alloc((size_t)N_NODES * 64 * 2);
  u16* hmid = (u16*)arena;
  u16* g1   = (u16*)arena;
  u16* abuf = (u16*)arena + (size_t)N_NODES * 64;
  u16* Bp_w2a = bpack;           // 8192
  u16* Bp_lw1 = bpack + 8192;    // 4096
  u16* Bp_lw2 = bpack + 12288;   // 4096
  u16* Bp_fw1 = bpack + 16384;   // 8192

  hipMemsetAsync(flag, 0, 16 + 384 * 4 + (size_t)N_NODES * 4 + NBKT * 4, stream);

  k_detect<<<1, 256, 0, stream>>>((const u16*)d_in[3], flag);

  CvtAll ca;
  const int srcidx[22] = {3, 4, 5, 6, 7, 8, 9, 10, 11, 12, 13, 14, 15, 16, 17, 18, 19, 20, 21, 22, 23, 24};
  const int cnts[22]   = {4160, 1024, 16384, 128, 8192, 64, 1, 64, 64, 4096, 64, 4096, 64, 1, 64, 64, 16384, 64, 64, 64, 64, 1};
  const int offs[22]   = {P_EMBD, P_EMBL, P_W1A, P_B1A, P_W2A, P_B2A, P_EPS0, P_G0, P_BB0,
                          P_LW1, P_LB1, P_LW2, P_LB2, P_EPS1, P_G1, P_BB1,
                          P_FW1, P_FB1, P_FG, P_FBB, P_FW2, P_FB2};
  for (int i = 0; i < 22; ++i) { ca.src[i] = d_in[srcidx[i]]; ca.cnt[i] = cnts[i]; ca.off[i] = offs[i]; }
  k_cvtall<<<dim3(64, 22), 256, 0, stream>>>(ca, flag, Pb);

  k_prep<<<157, 256, 0, stream>>>(Pb, W1p, Efc, bpack);

  // edge bucket-sort (dst>>9), then CSR from sorted edges
  k_bc<<<NCHK, 256, 0, stream>>>(edge, tcnt);
  k_bscan<<<1, 256, 0, stream>>>(tcnt, gcur);
  k_bsort<<<NCHK, 256, 0, stream>>>(edge, node_deg, node_lab, gcur, e2);
  k_deg2<<<(N_EDGES + 255) / 256, 256, 0, stream>>>(e2, deg);
  k_scan1<<<NBLK_SCAN, 256, 0, stream>>>(deg, row_ptr, bsum);
  k_scan2<<<1, 512, 0, stream>>>(bsum);
  k_fill2<<<(N_EDGES + 255) / 256, 256, 0, stream>>>(e2, row_ptr, bsum, einfo);

  const int GEMM_GRID = (6250 + 3) / 4;

  // layer 0
  k_agg0<<<(N_NODES + 63) / 64, 256, 0, stream>>>(row_ptr, bsum, einfo, node_deg, node_lab, W1p, Pb, hmid);
  k_gemm<4, 128, P_B2A><<<GEMM_GRID, 256, 0, stream>>>(hmid, Bp_w2a, Pb, t0);
  k_bnstats<<<512, 256, 0, stream>>>(t0, stats);

  // layer 1: BN fused into GEMM A-load; flat gather; GEMM
  k_gemm_bn<<<GEMM_GRID, 256, 0, stream>>>(t0, Bp_lw1, Pb, stats, g1);
  k_agg1<<<(N_NODES + 3) / 4, 256, 0, stream>>>(row_ptr, bsum, einfo, g1, Pb, abuf);
  k_gemm<2, 64, P_LB2><<<GEMM_GRID, 256, 0, stream>>>(abuf, Bp_lw2, Pb, t1);
  k_bnstats<<<512, 256, 0, stream>>>(t1, stats + 128);

  // FC head: BN0/BN1 fused into A-load
  k_gemm_fc1bn<<<GEMM_GRID, 256, 0, stream>>>(t0, t1, Bp_fw1, Pb, stats, node_deg, node_lab, Efc, t2);
  k_bnstats<<<512, 256, 0, stream>>>(t2, stats + 256);
  k_fc2<<<(N_NODES + 255) / 256, 256, 0, stream>>>(t2, stats + 256, Pb, flag, d_out);
}

// Round 11
// 480.552 us; speedup vs baseline: 1.2421x; 1.0322x over previous
//
#include <hip/hip_runtime.h>

#define N_NODES 100000
#define N_EDGES 1200000
#define NCLS 81   // 65 deg classes + 16 lab classes
#define NBKT 196  // dst>>9 buckets (512 nodes each)
#define NCHK 293  // ceil(N_EDGES/4096)

typedef unsigned short u16;
typedef unsigned char u8;
typedef unsigned int u32;
typedef unsigned long long u64;
typedef short bf16x8 __attribute__((ext_vector_type(8)));
typedef float f32x4 __attribute__((ext_vector_type(4)));

__device__ __forceinline__ float b2f(u16 u) {
  union { u32 i; float f; } v; v.i = ((u32)u) << 16; return v.f;
}
__device__ __forceinline__ u16 f2b(float f) {
  union { float f; u32 i; } v; v.f = f;
  u32 x = v.i;
  return (u16)((x + 0x7fffu + ((x >> 16) & 1u)) >> 16);
}
__device__ __forceinline__ u32 pk2(float lo, float hi) {
  return (u32)f2b(lo) | ((u32)f2b(hi) << 16);
}
__device__ __forceinline__ void up2(u32 w, float& lo, float& hi) {
  union { u32 u; float f; } a, b;
  a.u = w << 16; b.u = w & 0xffff0000u;
  lo = a.f; hi = b.f;
}
__device__ __forceinline__ float lrelu(float x) { return x > 0.f ? x : 0.01f * x; }

// ---- fp32 param block offsets ----
#define P_EMBD 0       // 4160
#define P_EMBL 4160    // 1024
#define P_W1A  5184    // 16384  l0_w1 (128x128)
#define P_B1A  21568   // 128
#define P_W2A  21696   // 8192   l0_w2 (128x64)
#define P_B2A  29888   // 64
#define P_EPS0 29952   // 1
#define P_G0   29953   // 64
#define P_BB0  30017   // 64
#define P_LW1  30081   // 4096   l1_w1 (64x64)
#define P_LB1  34177   // 64
#define P_LW2  34241   // 4096   l1_w2 (64x64)
#define P_LB2  38337   // 64
#define P_EPS1 38401   // 1
#define P_G1   38402   // 64
#define P_BB1  38466   // 64
#define P_FW1  38530   // 16384  fc_w1 (256x64)
#define P_FB1  54914   // 64
#define P_FG   54978   // 64
#define P_FBB  55042   // 64
#define P_FW2  55106   // 64
#define P_FB2  55170   // 1
#define P_TOT  55171

// ---------------- dtype detection ----------------
__global__ void k_detect(const u16* __restrict__ e, u32* __restrict__ flag) {
  u32 t = 0;
  for (int k = threadIdx.x; k < 4096; k += 256) {
    u32 ex = (e[k] >> 7) & 0xFF;
    if (ex >= 0x90) t = 1;
  }
  if (t) atomicOr(flag, 1u);
}

// ---------------- convert all float params to fp32 block ----------------
struct CvtAll {
  const void* src[22];
  int cnt[22];
  int off[22];
};

__global__ void k_cvtall(CvtAll a, const u32* __restrict__ flag, float* __restrict__ P) {
  int seg = blockIdx.y;
  int i = blockIdx.x * 256 + threadIdx.x;
  if (i >= a.cnt[seg]) return;
  float v;
  if (*flag) v = ((const float*)a.src[seg])[i];
  else       v = b2f(((const u16*)a.src[seg])[i]);
  P[a.off[seg] + i] = v;
}

// ---------------- merged preprocessing: W1p, Efc, MFMA B-pack ----------------
__global__ void k_prep(const float* __restrict__ P, float* __restrict__ W1p,
                       float* __restrict__ Efc, u16* __restrict__ bp) {
  int idx = blockIdx.x * 256 + threadIdx.x;
  if (idx < NCLS * 128) {
    int c = idx >> 7, h = idx & 127;
    const float* w1 = P + P_W1A;
    float s = 0.f;
    if (c < 65) {
      const float* em = P + P_EMBD + c * 64;
      for (int k = 0; k < 64; ++k) s = fmaf(em[k], w1[k * 128 + h], s);
    } else {
      const float* em = P + P_EMBL + (c - 65) * 64;
      for (int k = 0; k < 64; ++k) s = fmaf(em[k], w1[(64 + k) * 128 + h], s);
    }
    W1p[idx] = s;
    return;
  }
  if (idx < NCLS * 128 + NCLS * 64) {
    int r = idx - NCLS * 128;
    int c = r >> 6, o = r & 63;
    const float* fw = P + P_FW1;
    float s = 0.f;
    if (c < 65) {
      const float* em = P + P_EMBD + c * 64;
      for (int k = 0; k < 64; ++k) s = fmaf(em[k], fw[k * 64 + o], s);
    } else {
      const float* em = P + P_EMBL + (c - 65) * 64;
      for (int k = 0; k < 64; ++k) s = fmaf(em[k], fw[(64 + k) * 64 + o], s);
    }
    Efc[r] = s;
    return;
  }
  int pidx = idx - (NCLS * 128 + NCLS * 64);
  if (pidx >= 24576) return;
  int seg, rel;
  if (pidx < 8192)       { seg = 0; rel = pidx; }
  else if (pidx < 12288) { seg = 1; rel = pidx - 8192; }
  else if (pidx < 16384) { seg = 2; rel = pidx - 12288; }
  else                   { seg = 3; rel = pidx - 16384; }
  const int srcoff[4] = {P_W2A, P_LW1, P_LW2, P_FW1 + 128 * 64};
  const int KBs[4] = {4, 2, 2, 4};
  int j = rel & 7, lane = (rel >> 3) & 63, rest = rel >> 9;
  int kb = rest % KBs[seg], nt = rest / KBs[seg];
  int k = kb * 32 + (lane >> 4) * 8 + j;
  int n = nt * 16 + (lane & 15);
  bp[pidx] = f2b(P[srcoff[seg] + k * 64 + n]);
}

// ---------------- pack W1p into K=96 MFMA B-frag table (zero-pad rows 81..95) -------
__global__ void k_prep2(const float* __restrict__ W1p, u16* __restrict__ wpB) {
  int idx = blockIdx.x * 256 + threadIdx.x;
  if (idx >= 12288) return;
  int j = idx & 7, lane = (idx >> 3) & 63, rest = idx >> 9;  // rest in [0,24)
  int kb = rest % 3, nt = rest / 3;
  int c = kb * 32 + (lane >> 4) * 8 + j;   // class (K index), 0..95
  int n = nt * 16 + (lane & 15);           // output col, 0..127
  wpB[idx] = (c < NCLS) ? f2b(W1p[c * 128 + n]) : 0;
}

// ---------------- bucket counting-sort of edges by dst>>9 ----------------
__global__ __launch_bounds__(256) void k_bc(const int* __restrict__ edge, u32* __restrict__ tcnt) {
  __shared__ u32 c[NBKT];
  for (int i = threadIdx.x; i < NBKT; i += 256) c[i] = 0;
  __syncthreads();
  int base = blockIdx.x * 4096;
  for (int i = threadIdx.x; i < 4096; i += 256) {
    int e = base + i;
    if (e < N_EDGES) atomicAdd(&c[(u32)edge[N_EDGES + e] >> 9], 1u);
  }
  __syncthreads();
  for (int i = threadIdx.x; i < NBKT; i += 256)
    if (c[i]) atomicAdd(&tcnt[i], c[i]);
}

__global__ void k_bscan(const u32* __restrict__ tcnt, u32* __restrict__ gcur) {
  __shared__ u32 l[256];
  int tid = threadIdx.x;
  u32 v = (tid < NBKT) ? tcnt[tid] : 0u;
  l[tid] = v;
  __syncthreads();
  for (int off = 1; off < 256; off <<= 1) {
    u32 a = (tid >= off) ? l[tid - off] : 0u;
    __syncthreads();
    l[tid] += a;
    __syncthreads();
  }
  if (tid < NBKT) gcur[tid] = l[tid] - v;
}

__global__ __launch_bounds__(256) void k_bsort(const int* __restrict__ edge,
                                               const int* __restrict__ ndeg,
                                               const int* __restrict__ nlab,
                                               u32* __restrict__ gcur,
                                               u64* __restrict__ e2) {
  __shared__ u32 cnt[NBKT], rbase[NBKT];
  __shared__ u32 slo[4096], shi[4096];
  for (int i = threadIdx.x; i < NBKT; i += 256) cnt[i] = 0;
  __syncthreads();
  int base = blockIdx.x * 4096;
  for (int i = threadIdx.x; i < 4096; i += 256) {
    int e = base + i;
    if (e < N_EDGES) {
      int s = edge[e], d = edge[N_EDGES + e];
      slo[i] = ((u32)s << 11) | ((u32)ndeg[s] << 4) | (u32)nlab[s];
      shi[i] = (u32)d;
      atomicAdd(&cnt[(u32)d >> 9], 1u);
    } else shi[i] = 0xFFFFFFFFu;
  }
  __syncthreads();
  for (int i = threadIdx.x; i < NBKT; i += 256) {
    u32 c = cnt[i];
    rbase[i] = c ? atomicAdd(&gcur[i], c) : 0u;
    cnt[i] = 0;
  }
  __syncthreads();
  for (int i = threadIdx.x; i < 4096; i += 256) {
    u32 d = shi[i];
    if (d == 0xFFFFFFFFu) continue;
    u32 b = d >> 9;
    u32 pos = rbase[b] + atomicAdd(&cnt[b], 1u);
    e2[pos] = ((u64)d << 32) | (u64)slo[i];
  }
}

// ---------------- in-degree over dst-sorted edges ----------------
__global__ void k_deg2(const u64* __restrict__ e2, u32* __restrict__ deg) {
  int e = blockIdx.x * 256 + threadIdx.x;
  if (e >= N_EDGES) return;
  atomicAdd(&deg[(u32)(e2[e] >> 32)], 1u);
}

// ---------------- CSR scan ----------------
__global__ void k_scan1(const u32* __restrict__ deg, u32* __restrict__ row_ptr,
                        u32* __restrict__ bsum) {
  __shared__ u32 l[256];
  int tid = threadIdx.x;
  int i = blockIdx.x * 256 + tid;
  u32 v = (i < N_NODES) ? deg[i] : 0u;
  l[tid] = v;
  __syncthreads();
  for (int off = 1; off < 256; off <<= 1) {
    u32 a = (tid >= off) ? l[tid - off] : 0u;
    __syncthreads();
    l[tid] += a;
    __syncthreads();
  }
  if (i < N_NODES) row_ptr[i] = l[tid] - v;
  if (tid == 255) bsum[blockIdx.x] = l[255];
}

#define NBLK_SCAN 391

__global__ void k_scan2(u32* __restrict__ bsum) {
  __shared__ u32 l[512];
  int tid = threadIdx.x;
  u32 v = (tid < NBLK_SCAN) ? bsum[tid] : 0u;
  l[tid] = v;
  __syncthreads();
  for (int off = 1; off < 512; off <<= 1) {
    u32 a = (tid >= off) ? l[tid - off] : 0u;
    __syncthreads();
    l[tid] += a;
    __syncthreads();
  }
  if (tid < NBLK_SCAN) bsum[tid] = l[tid] - v;
}

// ---------------- CSR fill from sorted edges ----------------
__global__ void k_fill2(const u64* __restrict__ e2, u32* __restrict__ rp,
                        const u32* __restrict__ bsum, u32* __restrict__ einfo) {
  int e = blockIdx.x * 256 + threadIdx.x;
  if (e >= N_EDGES) return;
  u64 r = e2[e];
  u32 d = (u32)(r >> 32);
  u32 pos = atomicAdd(&rp[d], 1u) + bsum[d >> 8];
  einfo[pos] = (u32)r;
}

__device__ __forceinline__ u32 row_start(const u32* rp, const u32* bsum, int n) {
  return (n == 0) ? 0u : rp[n - 1] + bsum[(n - 1) >> 8];
}
__device__ __forceinline__ u32 row_end(const u32* rp, const u32* bsum, int n) {
  return rp[n] + bsum[n >> 8];
}

// ---------------- layer-0 class histogram: thread-per-node, private LDS ----------
__global__ __launch_bounds__(256) void k_hist(const u32* __restrict__ rp,
                                              const u32* __restrict__ bsum,
                                              const u32* __restrict__ einfo,
                                              u16* __restrict__ counts) {
  __shared__ u8 h[256 * 96];  // 24576 B
  int tid = threadIdx.x;
  u32* hw = (u32*)h;
#pragma unroll
  for (int i = 0; i < 24; ++i) hw[tid * 24 + i] = 0;
  __syncthreads();  // not strictly needed (private regions) but cheap
  int n = blockIdx.x * 256 + tid;
  if (n < N_NODES) {
    u32 st = row_start(rp, bsum, n), en = row_end(rp, bsum, n);
    u8* my = h + tid * 96;
    for (u32 e = st; e < en; ++e) {
      u32 q = einfo[e];
      ++my[(q >> 4) & 0x7Fu];
      ++my[65u + (q & 15u)];
    }
  }
  __syncthreads();
  // coalesced transposed writeout: block covers nodes [b0, b0+256)
  int b0 = blockIdx.x * 256;
  for (int idx = tid; idx < 256 * 96; idx += 256) {
    int nl = idx / 96;
    if (b0 + nl < N_NODES) counts[(size_t)(b0 + nl) * 96 + (idx - nl * 96)] = f2b((float)h[idx]);
  }
}

// ---------------- layer-0 MFMA GEMM: hmid = lrelu(counts@W1p + b1 + onep*self) -----
__global__ __launch_bounds__(256) void k_gemm0h(const u16* __restrict__ counts,
                                                const u16* __restrict__ wpB,
                                                const float* __restrict__ W1p,
                                                const float* __restrict__ P,
                                                const int* __restrict__ ndeg,
                                                const int* __restrict__ nlab,
                                                u16* __restrict__ hmid) {
  int wid = threadIdx.x >> 6, lane = threadIdx.x & 63;
  int m0 = (blockIdx.x * 4 + wid) * 16;
  if (m0 >= N_NODES) return;
  int row = lane & 15, q = lane >> 4;
  float onep = 1.f + P[P_EPS0];
  const u16* ap = counts + (size_t)(m0 + row) * 96 + q * 8;
  const bf16x8* bp = (const bf16x8*)wpB;
  f32x4 acc[8];
#pragma unroll
  for (int nt = 0; nt < 8; ++nt) {
    float b = P[P_B1A + nt * 16 + row];
    acc[nt][0] = b; acc[nt][1] = b; acc[nt][2] = b; acc[nt][3] = b;
  }
#pragma unroll
  for (int kb = 0; kb < 3; ++kb) {
    bf16x8 af = *(const bf16x8*)(ap + kb * 32);
#pragma unroll
    for (int nt = 0; nt < 8; ++nt) {
      bf16x8 bf = bp[(nt * 3 + kb) * 64 + lane];
      acc[nt] = __builtin_amdgcn_mfma_f32_16x16x32_bf16(af, bf, acc[nt], 0, 0, 0);
    }
  }
#pragma unroll
  for (int r = 0; r < 4; ++r) {
    int m = m0 + q * 4 + r;
    const float* wd = W1p + ndeg[m] * 128;
    const float* wl = W1p + (65 + nlab[m]) * 128;
#pragma unroll
    for (int nt = 0; nt < 8; ++nt) {
      int cc = nt * 16 + row;
      float v = acc[nt][r] + onep * (wd[cc] + wl[cc]);
      hmid[(size_t)m * 128 + cc] = f2b(lrelu(v));
    }
  }
}

// ---------------- MFMA GEMM (plain): C = A @ B + bias ----------------
template <int KB, int LDA, int BIASOFF>
__global__ __launch_bounds__(256) void k_gemm(const u16* __restrict__ A,
                                              const u16* __restrict__ Bp,
                                              const float* __restrict__ P,
                                              u16* __restrict__ C) {
  int wid = threadIdx.x >> 6, lane = threadIdx.x & 63;
  int m0 = (blockIdx.x * 4 + wid) * 16;
  if (m0 >= N_NODES) return;
  int row = lane & 15, q = lane >> 4;
  const u16* ap = A + (size_t)(m0 + row) * LDA + q * 8;
  const bf16x8* bp = (const bf16x8*)Bp;
  f32x4 acc[4];
#pragma unroll
  for (int nt = 0; nt < 4; ++nt) {
    float b = (BIASOFF >= 0) ? P[BIASOFF + nt * 16 + row] : 0.f;
    acc[nt][0] = b; acc[nt][1] = b; acc[nt][2] = b; acc[nt][3] = b;
  }
#pragma unroll
  for (int kb = 0; kb < KB; ++kb) {
    bf16x8 af = *(const bf16x8*)(ap + kb * 32);
#pragma unroll
    for (int nt = 0; nt < 4; ++nt) {
      bf16x8 bf = bp[(nt * KB + kb) * 64 + lane];
      acc[nt] = __builtin_amdgcn_mfma_f32_16x16x32_bf16(af, bf, acc[nt], 0, 0, 0);
    }
  }
#pragma unroll
  for (int nt = 0; nt < 4; ++nt)
#pragma unroll
    for (int r = 0; r < 4; ++r) {
      int m = m0 + q * 4 + r;
      C[(size_t)m * 64 + nt * 16 + row] = f2b(acc[nt][r]);
    }
}

// ---------------- MFMA GEMM with fused BN+lrelu on A (K=64) ----------------
__global__ __launch_bounds__(256) void k_gemm_bn(const u16* __restrict__ A,
                                                 const u16* __restrict__ Bp,
                                                 const float* __restrict__ P,
                                                 const float* __restrict__ stats,
                                                 u16* __restrict__ C) {
  int wid = threadIdx.x >> 6, lane = threadIdx.x & 63;
  int m0 = (blockIdx.x * 4 + wid) * 16;
  if (m0 >= N_NODES) return;
  int row = lane & 15, q = lane >> 4;
  const float invN = 1.f / (float)N_NODES;
  float sc[16], sh[16];
#pragma unroll
  for (int kb = 0; kb < 2; ++kb)
#pragma unroll
    for (int j = 0; j < 8; ++j) {
      int f = kb * 32 + q * 8 + j;
      float mm = stats[f] * invN;
      float var = fmaxf(stats[64 + f] * invN - mm * mm, 0.f);
      float inv = rsqrtf(var + 1e-5f);
      float s = inv * P[P_G0 + f];
      sc[kb * 8 + j] = s;
      sh[kb * 8 + j] = P[P_BB0 + f] - mm * s;
    }
  const u16* ap = A + (size_t)(m0 + row) * 64 + q * 8;
  const bf16x8* bp = (const bf16x8*)Bp;
  f32x4 acc[4];
#pragma unroll
  for (int nt = 0; nt < 4; ++nt) {
    acc[nt][0] = 0.f; acc[nt][1] = 0.f; acc[nt][2] = 0.f; acc[nt][3] = 0.f;
  }
#pragma unroll
  for (int kb = 0; kb < 2; ++kb) {
    uint4 raw = *(const uint4*)(ap + kb * 32);
    u32 rw[4] = {raw.x, raw.y, raw.z, raw.w};
    bf16x8 af;
#pragma unroll
    for (int p = 0; p < 4; ++p) {
      float lo, hi;
      up2(rw[p], lo, hi);
      float y0 = lrelu(fmaf(sc[kb * 8 + 2 * p], lo, sh[kb * 8 + 2 * p]));
      float y1 = lrelu(fmaf(sc[kb * 8 + 2 * p + 1], hi, sh[kb * 8 + 2 * p + 1]));
      af[2 * p] = (short)f2b(y0);
      af[2 * p + 1] = (short)f2b(y1);
    }
#pragma unroll
    for (int nt = 0; nt < 4; ++nt) {
      bf16x8 bf = bp[(nt * 2 + kb) * 64 + lane];
      acc[nt] = __builtin_amdgcn_mfma_f32_16x16x32_bf16(af, bf, acc[nt], 0, 0, 0);
    }
  }
#pragma unroll
  for (int nt = 0; nt < 4; ++nt)
#pragma unroll
    for (int r = 0; r < 4; ++r) {
      int m = m0 + q * 4 + r;
      C[(size_t)m * 64 + nt * 16 + row] = f2b(acc[nt][r]);
    }
}

// ---------------- fc1 GEMM: A = [BN0(t0) | BN1(t1)] fused, + Efc epilogue ----------
__global__ __launch_bounds__(256) void k_gemm_fc1bn(const u16* __restrict__ t0,
                                                    const u16* __restrict__ t1,
                                                    const u16* __restrict__ Bp,
                                                    const float* __restrict__ P,
                                                    const float* __restrict__ stats,
                                                    const int* __restrict__ ndeg,
                                                    const int* __restrict__ nlab,
                                                    const float* __restrict__ Efc,
                                                    u16* __restrict__ C) {
  int wid = threadIdx.x >> 6, lane = threadIdx.x & 63;
  int m0 = (blockIdx.x * 4 + wid) * 16;
  if (m0 >= N_NODES) return;
  int row = lane & 15, q = lane >> 4;
  const float invN = 1.f / (float)N_NODES;
  float sc[32], sh[32];
#pragma unroll
  for (int h = 0; h < 2; ++h) {
    const float* st = stats + h * 128;
    int gof = h ? P_G1 : P_G0, bof = h ? P_BB1 : P_BB0;
#pragma unroll
    for (int kb = 0; kb < 2; ++kb)
#pragma unroll
      for (int j = 0; j < 8; ++j) {
        int f = kb * 32 + q * 8 + j;
        float mm = st[f] * invN;
        float var = fmaxf(st[64 + f] * invN - mm * mm, 0.f);
        float inv = rsqrtf(var + 1e-5f);
        float s = inv * P[gof + f];
        sc[h * 16 + kb * 8 + j] = s;
        sh[h * 16 + kb * 8 + j] = P[bof + f] - mm * s;
      }
  }
  const u16* a0 = t0 + (size_t)(m0 + row) * 64 + q * 8;
  const u16* a1 = t1 + (size_t)(m0 + row) * 64 + q * 8;
  const bf16x8* bp = (const bf16x8*)Bp;
  f32x4 acc[4];
#pragma unroll
  for (int nt = 0; nt < 4; ++nt) {
    float b = P[P_FB1 + nt * 16 + row];
    acc[nt][0] = b; acc[nt][1] = b; acc[nt][2] = b; acc[nt][3] = b;
  }
#pragma unroll
  for (int kb = 0; kb < 4; ++kb) {
    const u16* src = (kb < 2) ? (a0 + kb * 32) : (a1 + (kb - 2) * 32);
    int ci = (kb < 2) ? kb * 8 : 16 + (kb - 2) * 8;
    uint4 raw = *(const uint4*)src;
    u32 rw[4] = {raw.x, raw.y, raw.z, raw.w};
    bf16x8 af;
#pragma unroll
    for (int p = 0; p < 4; ++p) {
      float lo, hi;
      up2(rw[p], lo, hi);
      float y0 = lrelu(fmaf(sc[ci + 2 * p], lo, sh[ci + 2 * p]));
      float y1 = lrelu(fmaf(sc[ci + 2 * p + 1], hi, sh[ci + 2 * p + 1]));
      af[2 * p] = (short)f2b(y0);
      af[2 * p + 1] = (short)f2b(y1);
    }
#pragma unroll
    for (int nt = 0; nt < 4; ++nt) {
      bf16x8 bf = bp[(nt * 4 + kb) * 64 + lane];
      acc[nt] = __builtin_amdgcn_mfma_f32_16x16x32_bf16(af, bf, acc[nt], 0, 0, 0);
    }
  }
#pragma unroll
  for (int r = 0; r < 4; ++r) {
    int m = m0 + q * 4 + r;
    int dn = ndeg[m], ln = 65 + nlab[m];
#pragma unroll
    for (int nt = 0; nt < 4; ++nt) {
      int cc = nt * 16 + row;
      float v = acc[nt][r] + Efc[dn * 64 + cc] + Efc[ln * 64 + cc];
      C[(size_t)m * 64 + cc] = f2b(v);
    }
  }
}

// ---------------- layer-1 aggregation: flat gather, 8-deep, 2 acc chains ----------
__global__ __launch_bounds__(256) void k_agg1(const u32* __restrict__ rp,
                                              const u32* __restrict__ bsum,
                                              const u32* __restrict__ einfo,
                                              const u16* __restrict__ g1,
                                              const float* __restrict__ P,
                                              u16* __restrict__ abuf) {
  int lane = threadIdx.x & 63, wv = threadIdx.x >> 6;
  int n = blockIdx.x * 4 + wv;
  if (n >= N_NODES) return;
  u32 st = row_start(rp, bsum, n), en = row_end(rp, bsum, n);
  u32 m = en - st;
  float acA = 0.f, acB = 0.f;
  u32 k = 0;
  for (; k + 8 <= m; k += 8) {
    u32 c0 = einfo[st + k] >> 11, c1 = einfo[st + k + 1] >> 11;
    u32 c2 = einfo[st + k + 2] >> 11, c3 = einfo[st + k + 3] >> 11;
    u32 c4 = einfo[st + k + 4] >> 11, c5 = einfo[st + k + 5] >> 11;
    u32 c6 = einfo[st + k + 6] >> 11, c7 = einfo[st + k + 7] >> 11;
    float v0 = b2f(g1[(size_t)c0 * 64 + lane]);
    float v1 = b2f(g1[(size_t)c1 * 64 + lane]);
    float v2 = b2f(g1[(size_t)c2 * 64 + lane]);
    float v3 = b2f(g1[(size_t)c3 * 64 + lane]);
    float v4 = b2f(g1[(size_t)c4 * 64 + lane]);
    float v5 = b2f(g1[(size_t)c5 * 64 + lane]);
    float v6 = b2f(g1[(size_t)c6 * 64 + lane]);
    float v7 = b2f(g1[(size_t)c7 * 64 + lane]);
    acA += (v0 + v1) + (v2 + v3);
    acB += (v4 + v5) + (v6 + v7);
  }
  if (k + 4 <= m) {
    u32 c0 = einfo[st + k] >> 11, c1 = einfo[st + k + 1] >> 11;
    u32 c2 = einfo[st + k + 2] >> 11, c3 = einfo[st + k + 3] >> 11;
    float v0 = b2f(g1[(size_t)c0 * 64 + lane]);
    float v1 = b2f(g1[(size_t)c1 * 64 + lane]);
    float v2 = b2f(g1[(size_t)c2 * 64 + lane]);
    float v3 = b2f(g1[(size_t)c3 * 64 + lane]);
    acA += (v0 + v1) + (v2 + v3);
    k += 4;
  }
  for (; k < m; ++k) acB += b2f(g1[(size_t)(einfo[st + k] >> 11) * 64 + lane]);
  float acc = acA + acB;
  float onep = 1.f + P[P_EPS1];
  float a = P[P_LB1 + lane] + fmaf(onep, b2f(g1[(size_t)n * 64 + lane]), acc);
  abuf[(size_t)n * 64 + lane] = f2b(lrelu(a));
}

// ---------------- BatchNorm stats over bf16 t ----------------
__global__ void k_bnstats(const u16* __restrict__ t, float* __restrict__ stats) {
  __shared__ float ls[256], lq[256];
  int tid = threadIdx.x;
  int f = tid & 63, rg = tid >> 6;
  float s = 0.f, q = 0.f;
  for (int n = blockIdx.x * 4 + rg; n < N_NODES; n += gridDim.x * 4) {
    float v = b2f(t[(size_t)n * 64 + f]);
    s += v;
    q = fmaf(v, v, q);
  }
  ls[tid] = s; lq[tid] = q;
  __syncthreads();
  if (tid < 64) {
    s = ls[tid] + ls[tid + 64] + ls[tid + 128] + ls[tid + 192];
    q = lq[tid] + lq[tid + 64] + lq[tid + 128] + lq[tid + 192];
    atomicAdd(&stats[f], s);
    atomicAdd(&stats[64 + f], q);
  }
}

// ---------------- FC final: BN + lrelu + dot + sigmoid ----------------
__global__ void k_fc2(const u16* __restrict__ t, const float* __restrict__ stats,
                      const float* __restrict__ P, const u32* __restrict__ flag,
                      void* __restrict__ out) {
  int n = blockIdx.x * blockDim.x + threadIdx.x;
  if (n >= N_NODES) return;
  float z = P[P_FB2];
  const float invN = 1.f / (float)N_NODES;
  const u16* tn = t + (size_t)n * 64;
#pragma unroll 1
  for (int f = 0; f < 64; ++f) {
    float m = stats[f] * invN;
    float var = fmaxf(stats[64 + f] * invN - m * m, 0.f);
    float inv = rsqrtf(var + 1e-5f);
    float y = (b2f(tn[f]) - m) * inv * P[P_FG + f] + P[P_FBB + f];
    y = lrelu(y);
    z = fmaf(y, P[P_FW2 + f], z);
  }
  float s = 1.f / (1.f + expf(-z));
  if (!(fabsf(z) < 1e30f)) s = 0.25f;
  if (*flag) ((float*)out)[n] = s;
  else       ((u16*)out)[n] = f2b(s);
}

extern "C" void kernel_launch(void* const* d_in, const int* in_sizes, int n_in,
                              void* d_out, int out_size, void* d_ws, size_t ws_size,
                              hipStream_t stream) {
  const int* node_deg = (const int*)d_in[0];
  const int* node_lab = (const int*)d_in[1];
  const int* edge     = (const int*)d_in[2];
  (void)in_sizes; (void)n_in; (void)out_size; (void)ws_size;

  char* base = (char*)d_ws;
  size_t off = 0;
  auto alloc = [&](size_t bytes) -> void* {
    void* p = base + off;
    off += (bytes + 15) & ~(size_t)15;
    return p;
  };
  float* Pb    = (float*)alloc((size_t)P_TOT * 4);
  // contiguous zero region: flag | stats | deg | tcnt (one memset)
  u32* flag    = (u32*)alloc(16);
  float* stats = (float*)alloc(384 * 4);
  u32* deg     = (u32*)alloc((size_t)N_NODES * 4);
  u32* tcnt    = (u32*)alloc(NBKT * 4);
  float* W1p   = (float*)alloc(NCLS * 128 * 4);
  float* Efc   = (float*)alloc(NCLS * 64 * 4);
  u16* bpack   = (u16*)alloc(24576 * 2);
  u16* wpB     = (u16*)alloc(12288 * 2);
  u32* row_ptr = (u32*)alloc((size_t)(N_NODES + 1) * 4);
  u32* bsum    = (u32*)alloc(512 * 4);
  u32* gcur    = (u32*)alloc(NBKT * 4);
  u32* einfo   = (u32*)alloc((size_t)N_EDGES * 4);
  u64* e2      = (u64*)alloc((size_t)N_EDGES * 8);
  void* arena  = alloc((size_t)N_NODES * 128 * 2);  // hmid; later g1+abuf
  u16* t0      = (u16*)alloc((size_t)N_NODES * 64 * 2);
  u16* t1      = (u16*)alloc((size_t)N_NODES * 64 * 2);
  u16* t2      = (u16*)alloc((size_t)N_NODES * 64 * 2);
  u16* hmid = (u16*)arena;
  u16* g1   = (u16*)arena;
  u16* abuf = (u16*)arena + (size_t)N_NODES * 64;
  u16* counts = t1;  // [N,96] bf16 overlays t1+t2 head; dead before t1/t2 written
  u16* Bp_w2a = bpack;           // 8192
  u16* Bp_lw1 = bpack + 8192;    // 4096
  u16* Bp_lw2 = bpack + 12288;   // 4096
  u16* Bp_fw1 = bpack + 16384;   // 8192

  hipMemsetAsync(flag, 0, 16 + 384 * 4 + (size_t)N_NODES * 4 + NBKT * 4, stream);

  k_detect<<<1, 256, 0, stream>>>((const u16*)d_in[3], flag);

  CvtAll ca;
  const int srcidx[22] = {3, 4, 5, 6, 7, 8, 9, 10, 11, 12, 13, 14, 15, 16, 17, 18, 19, 20, 21, 22, 23, 24};
  const int cnts[22]   = {4160, 1024, 16384, 128, 8192, 64, 1, 64, 64, 4096, 64, 4096, 64, 1, 64, 64, 16384, 64, 64, 64, 64, 1};
  const int offs[22]   = {P_EMBD, P_EMBL, P_W1A, P_B1A, P_W2A, P_B2A, P_EPS0, P_G0, P_BB0,
                          P_LW1, P_LB1, P_LW2, P_LB2, P_EPS1, P_G1, P_BB1,
                          P_FW1, P_FB1, P_FG, P_FBB, P_FW2, P_FB2};
  for (int i = 0; i < 22; ++i) { ca.src[i] = d_in[srcidx[i]]; ca.cnt[i] = cnts[i]; ca.off[i] = offs[i]; }
  k_cvtall<<<dim3(64, 22), 256, 0, stream>>>(ca, flag, Pb);

  k_prep<<<157, 256, 0, stream>>>(Pb, W1p, Efc, bpack);
  k_prep2<<<48, 256, 0, stream>>>(W1p, wpB);

  // edge bucket-sort (dst>>9), then CSR from sorted edges
  k_bc<<<NCHK, 256, 0, stream>>>(edge, tcnt);
  k_bscan<<<1, 256, 0, stream>>>(tcnt, gcur);
  k_bsort<<<NCHK, 256, 0, stream>>>(edge, node_deg, node_lab, gcur, e2);
  k_deg2<<<(N_EDGES + 255) / 256, 256, 0, stream>>>(e2, deg);
  k_scan1<<<NBLK_SCAN, 256, 0, stream>>>(deg, row_ptr, bsum);
  k_scan2<<<1, 512, 0, stream>>>(bsum);
  k_fill2<<<(N_EDGES + 255) / 256, 256, 0, stream>>>(e2, row_ptr, bsum, einfo);

  const int GEMM_GRID = (6250 + 3) / 4;

  // layer 0: histogram -> MFMA GEMM (K=96) -> t0
  k_hist<<<(N_NODES + 255) / 256, 256, 0, stream>>>(row_ptr, bsum, einfo, counts);
  k_gemm0h<<<GEMM_GRID, 256, 0, stream>>>(counts, wpB, W1p, Pb, node_deg, node_lab, hmid);
  k_gemm<4, 128, P_B2A><<<GEMM_GRID, 256, 0, stream>>>(hmid, Bp_w2a, Pb, t0);
  k_bnstats<<<512, 256, 0, stream>>>(t0, stats);

  // layer 1: BN fused into GEMM A-load; flat gather; GEMM
  k_gemm_bn<<<GEMM_GRID, 256, 0, stream>>>(t0, Bp_lw1, Pb, stats, g1);
  k_agg1<<<(N_NODES + 3) / 4, 256, 0, stream>>>(row_ptr, bsum, einfo, g1, Pb, abuf);
  k_gemm<2, 64, P_LB2><<<GEMM_GRID, 256, 0, stream>>>(abuf, Bp_lw2, Pb, t1);
  k_bnstats<<<512, 256, 0, stream>>>(t1, stats + 128);

  // FC head: BN0/BN1 fused into A-load
  k_gemm_fc1bn<<<GEMM_GRID, 256, 0, stream>>>(t0, t1, Bp_fw1, Pb, stats, node_deg, node_lab, Efc, t2);
  k_bnstats<<<512, 256, 0, stream>>>(t2, stats + 256);
  k_fc2<<<(N_NODES + 255) / 256, 256, 0, stream>>>(t2, stats + 256, Pb, flag, d_out);
}